// Round 3
// baseline (204.157 us; speedup 1.0000x reference)
//
#include <hip/hip_runtime.h>
#include <hip/hip_bf16.h>
#include <stdint.h>

// SymmetricLoss: symmetric InfoNCE over cosine logits.
// loss = mean_i[ 0.5*(log rowsum_i + log colsum_i) - S_ii ],
// S = Xn·Ynᵀ / tau.  |S|<=2 so exp needs no max subtraction.
//
// GEMM kernel: 256x256 tile, BK=64, 8 waves, 4-phase/K-tile schedule (T3+T4)
// with counted vmcnt(6), raw s_barrier, setprio (T5), XOR-swizzled LDS via
// pre-swizzled global source (T2, rule #21). Fragment loads are INLINE-ASM
// ds_read_b128 so the compiler cannot insert vmcnt(0) ordering vs the
// global_load_lds stages (that ordering serialized R2 at 21% MfmaUtil);
// correctness carried by explicit lgkmcnt(0)+sched_barrier(0) (rule #18).

#define NROWS 8192
#define DDIM  512
#define TAU_INV 2.0f
#define KT 8            // DDIM / 64 K-tiles

typedef __bf16 bf16x8 __attribute__((ext_vector_type(8)));
typedef __bf16 bf16x4 __attribute__((ext_vector_type(4)));
typedef float  f32x4  __attribute__((ext_vector_type(4)));
typedef __attribute__((address_space(3))) const __bf16 lds_cbf16;

__device__ __forceinline__ bf16x8 ds_read8(lds_cbf16* p) {
  bf16x8 r;
  asm volatile("ds_read_b128 %0, %1" : "=v"(r) : "v"(p));
  return r;
}

// ---------------- kernel 1: row-normalize x,y -> bf16 (+ zero accumulators) ----------------
__global__ __launch_bounds__(256) void normalize_kernel(
    const float* __restrict__ x, const float* __restrict__ y,
    __bf16* __restrict__ xn, __bf16* __restrict__ yn,
    float* __restrict__ rowsum, float* __restrict__ colsum,
    float* __restrict__ out) {
  const int idx = blockIdx.x * 256 + (int)threadIdx.x;
  if (idx < NROWS) { rowsum[idx] = 0.0f; colsum[idx] = 0.0f; }
  if (idx == 0) out[0] = 0.0f;

  const int wave = threadIdx.x >> 6;
  const int lane = threadIdx.x & 63;
  const int row  = blockIdx.x * 4 + wave;   // 0..16383: first 8192 = x, rest = y
  const float* src;
  __bf16* dst;
  if (row < NROWS) { src = x + (size_t)row * DDIM;           dst = xn + (size_t)row * DDIM; }
  else             { src = y + (size_t)(row - NROWS) * DDIM; dst = yn + (size_t)(row - NROWS) * DDIM; }

  const float4* s4 = (const float4*)src;
  float4 v0 = s4[lane];
  float4 v1 = s4[lane + 64];
  float ss = v0.x*v0.x + v0.y*v0.y + v0.z*v0.z + v0.w*v0.w
           + v1.x*v1.x + v1.y*v1.y + v1.z*v1.z + v1.w*v1.w;
  #pragma unroll
  for (int off = 1; off < 64; off <<= 1) ss += __shfl_xor(ss, off);
  const float rn = 1.0f / fmaxf(sqrtf(ss), 1e-8f);

  bf16x4 o0, o1;
  o0[0]=(__bf16)(v0.x*rn); o0[1]=(__bf16)(v0.y*rn); o0[2]=(__bf16)(v0.z*rn); o0[3]=(__bf16)(v0.w*rn);
  o1[0]=(__bf16)(v1.x*rn); o1[1]=(__bf16)(v1.y*rn); o1[2]=(__bf16)(v1.z*rn); o1[3]=(__bf16)(v1.w*rn);
  *(bf16x4*)(dst + 4*lane)       = o0;
  *(bf16x4*)(dst + 256 + 4*lane) = o1;
}

// Stage one 128-row half-tile (128 x 64 bf16 = 16 KB): 2 x global_load_lds(16B)/thread.
// LDS dest linear; source column-chunk pre-swizzled cc^(r&7) (involution, rule #21).
__device__ __forceinline__ void stage_half(const __bf16* __restrict__ M,
                                           int trow0, int kt, __bf16* lds, int tid) {
  const int r0 = tid >> 3;                       // 0..63
  const int sc = (tid & 7) ^ (r0 & 7);
  const __bf16* src = M + (size_t)(trow0 + r0) * DDIM + kt * 64 + sc * 8;
  __builtin_amdgcn_global_load_lds((__attribute__((address_space(1))) void*)src,
      (__attribute__((address_space(3))) void*)(lds + tid * 8), 16, 0, 0);
  __builtin_amdgcn_global_load_lds((__attribute__((address_space(1))) void*)(src + 64 * DDIM),
      (__attribute__((address_space(3))) void*)(lds + 4096 + tid * 8), 16, 0, 0);
}

#define PHASE_SYNC_PRE()  do { __builtin_amdgcn_sched_barrier(0); \
                               __builtin_amdgcn_s_barrier(); \
                               asm volatile("s_waitcnt lgkmcnt(0)" ::: "memory"); \
                               __builtin_amdgcn_sched_barrier(0); \
                               __builtin_amdgcn_s_setprio(1); } while (0)
#define PHASE_SYNC_POST() do { __builtin_amdgcn_s_setprio(0); \
                               __builtin_amdgcn_sched_barrier(0); } while (0)

// ---------------- kernel 2: fused 256^2-tile GEMM + exp + row/col sums ----------------
__global__ __launch_bounds__(512, 2) void gemm_exp_kernel(
    const __bf16* __restrict__ Xn, const __bf16* __restrict__ Yn,
    float* __restrict__ rowsum, float* __restrict__ colsum,
    float* __restrict__ diag) {
  // LDS: A bufs at 0 / 16384, B bufs at 32768 / 49152 (elems). 128 KiB total.
  __shared__ __bf16 sm[65536];

  const int tid  = threadIdx.x;
  const int lane = tid & 63;
  const int w    = tid >> 6;
  const int wr   = w >> 2;            // 0..1
  const int wc   = w & 3;             // 0..3
  const int bi = blockIdx.y, bj = blockIdx.x;

  const int l15 = lane & 15;
  const int g   = lane >> 4;          // 0..3
  const int lx  = lane & 7;
  const int sc0 = g ^ lx;             // swizzled chunk, ks=0
  const int sc1 = (4 + g) ^ lx;       // ks=1
  const int arow = wr * 64 + l15;     // + mi*16 (+128 for hi)
  const int brow = wc * 32 + l15;     // + ni*16 (+128 for hi)

  const int Ar = bi * 256;            // global row base (X)
  const int Br = bj * 256;            // global col base (Y)

  f32x4 acc[8][4] = {};

  // ---- prologue: 7 half-tiles, vmcnt 4 -> 6 ----
  stage_half(Xn, Ar,       0, sm + 0,                     tid);  // A-lo(0)
  stage_half(Yn, Br,       0, sm + 32768,                 tid);  // B-lo(0)
  stage_half(Yn, Br + 128, 0, sm + 32768 + 8192,          tid);  // B-hi(0)
  stage_half(Xn, Ar + 128, 0, sm + 8192,                  tid);  // A-hi(0)
  asm volatile("s_waitcnt vmcnt(4)" ::: "memory");
  stage_half(Xn, Ar,       1, sm + 16384,                 tid);  // A-lo(1)
  stage_half(Yn, Br,       1, sm + 32768 + 16384,         tid);  // B-lo(1)
  stage_half(Yn, Br + 128, 1, sm + 32768 + 16384 + 8192,  tid);  // B-hi(1)
  asm volatile("s_waitcnt vmcnt(6)" ::: "memory");
  __builtin_amdgcn_s_barrier();

  for (int t = 0; t < KT; ++t) {
    const int cbuf = t & 1, nbuf = cbuf ^ 1;
    lds_cbf16* As = (lds_cbf16*)(sm + cbuf * 16384);
    lds_cbf16* Bs = (lds_cbf16*)(sm + 32768 + cbuf * 16384);
    bf16x8 aq[2][4], blo[2][2], bhi[2][2];

    // ======== phase 1: acc[0..3][0..1]  (reads A-lo, B-lo) ========
    #pragma unroll
    for (int mi = 0; mi < 4; ++mi) {
      aq[0][mi] = ds_read8(As + (arow + mi*16)*64 + sc0*8);
      aq[1][mi] = ds_read8(As + (arow + mi*16)*64 + sc1*8);
    }
    #pragma unroll
    for (int ni = 0; ni < 2; ++ni) {
      blo[0][ni] = ds_read8(Bs + (brow + ni*16)*64 + sc0*8);
      blo[1][ni] = ds_read8(Bs + (brow + ni*16)*64 + sc1*8);
    }
    if (t < KT-1) stage_half(Xn, Ar + 128, t+1, sm + nbuf*16384 + 8192, tid);  // A-hi(t+1)
    PHASE_SYNC_PRE();
    #pragma unroll
    for (int mi = 0; mi < 4; ++mi)
      #pragma unroll
      for (int ni = 0; ni < 2; ++ni) {
        acc[mi][ni] = __builtin_amdgcn_mfma_f32_16x16x32_bf16(aq[0][mi], blo[0][ni], acc[mi][ni], 0,0,0);
        acc[mi][ni] = __builtin_amdgcn_mfma_f32_16x16x32_bf16(aq[1][mi], blo[1][ni], acc[mi][ni], 0,0,0);
      }
    PHASE_SYNC_POST();
    if (t == KT-1) asm volatile("s_waitcnt vmcnt(2)" ::: "memory");  // tail: B-hi(7) landed
    __builtin_amdgcn_s_barrier();

    // ======== phase 2: acc[0..3][2..3]  (reads B-hi; reuses aq) ========
    #pragma unroll
    for (int ni = 0; ni < 2; ++ni) {
      bhi[0][ni] = ds_read8(Bs + (128 + brow + ni*16)*64 + sc0*8);
      bhi[1][ni] = ds_read8(Bs + (128 + brow + ni*16)*64 + sc1*8);
    }
    if (t < KT-2) stage_half(Xn, Ar, t+2, sm + cbuf*16384, tid);               // A-lo(t+2)
    PHASE_SYNC_PRE();
    #pragma unroll
    for (int mi = 0; mi < 4; ++mi)
      #pragma unroll
      for (int ni = 0; ni < 2; ++ni) {
        acc[mi][2+ni] = __builtin_amdgcn_mfma_f32_16x16x32_bf16(aq[0][mi], bhi[0][ni], acc[mi][2+ni], 0,0,0);
        acc[mi][2+ni] = __builtin_amdgcn_mfma_f32_16x16x32_bf16(aq[1][mi], bhi[1][ni], acc[mi][2+ni], 0,0,0);
      }
    PHASE_SYNC_POST();
    if (t == KT-1) asm volatile("s_waitcnt vmcnt(0)" ::: "memory");  // tail: A-hi(7) landed
    __builtin_amdgcn_s_barrier();

    // ======== phase 3: acc[4..7][0..1]  (reads A-hi; reuses blo) ========
    #pragma unroll
    for (int mi = 0; mi < 4; ++mi) {
      aq[0][mi] = ds_read8(As + (128 + arow + mi*16)*64 + sc0*8);
      aq[1][mi] = ds_read8(As + (128 + arow + mi*16)*64 + sc1*8);
    }
    if (t < KT-2) stage_half(Yn, Br, t+2, sm + 32768 + cbuf*16384, tid);       // B-lo(t+2)
    PHASE_SYNC_PRE();
    #pragma unroll
    for (int mi = 0; mi < 4; ++mi)
      #pragma unroll
      for (int ni = 0; ni < 2; ++ni) {
        acc[4+mi][ni] = __builtin_amdgcn_mfma_f32_16x16x32_bf16(aq[0][mi], blo[0][ni], acc[4+mi][ni], 0,0,0);
        acc[4+mi][ni] = __builtin_amdgcn_mfma_f32_16x16x32_bf16(aq[1][mi], blo[1][ni], acc[4+mi][ni], 0,0,0);
      }
    PHASE_SYNC_POST();
    __builtin_amdgcn_s_barrier();

    // ======== phase 4: acc[4..7][2..3]  (no new reads) ========
    if (t < KT-2) stage_half(Yn, Br + 128, t+2, sm + 32768 + cbuf*16384 + 8192, tid); // B-hi(t+2)
    PHASE_SYNC_PRE();
    #pragma unroll
    for (int mi = 0; mi < 4; ++mi)
      #pragma unroll
      for (int ni = 0; ni < 2; ++ni) {
        acc[4+mi][2+ni] = __builtin_amdgcn_mfma_f32_16x16x32_bf16(aq[0][mi], bhi[0][ni], acc[4+mi][2+ni], 0,0,0);
        acc[4+mi][2+ni] = __builtin_amdgcn_mfma_f32_16x16x32_bf16(aq[1][mi], bhi[1][ni], acc[4+mi][2+ni], 0,0,0);
      }
    PHASE_SYNC_POST();
    // once-per-K-tile counted check: tile t+1 fully landed; 3 newest half-tiles
    // (for t+2) stay in flight (T4: never drain to 0 mid-loop).
    if (t < KT-2)       { asm volatile("s_waitcnt vmcnt(6)" ::: "memory"); }
    else if (t == KT-2) { asm volatile("s_waitcnt vmcnt(4)" ::: "memory"); }
    __builtin_amdgcn_s_barrier();
  }

  // ---------------- epilogue ----------------
  // C mapping (verified): row = frag_row_base + g*4 + reg, col = frag_col_base + l15
  int RL[8], CL[4];
  #pragma unroll
  for (int m = 0; m < 8; ++m) RL[m] = (m < 4) ? (wr*64 + m*16) : (128 + wr*64 + (m-4)*16);
  #pragma unroll
  for (int n = 0; n < 4; ++n) CL[n] = (n < 2) ? (wc*32 + n*16) : (128 + wc*32 + (n-2)*16);

  // diag (pre-exp logits), only diagonal blocks
  if (bi == bj) {
    #pragma unroll
    for (int m = 0; m < 8; ++m)
      #pragma unroll
      for (int n = 0; n < 4; ++n)
        #pragma unroll
        for (int r = 0; r < 4; ++r) {
          const int rl = RL[m] + g*4 + r, cl = CL[n] + l15;
          if (rl == cl) diag[bi*256 + rl] = TAU_INV * acc[m][n][r];
        }
  }

  // exp in place
  #pragma unroll
  for (int m = 0; m < 8; ++m)
    #pragma unroll
    for (int n = 0; n < 4; ++n)
      #pragma unroll
      for (int r = 0; r < 4; ++r)
        acc[m][n][r] = __expf(TAU_INV * acc[m][n][r]);

  // row sums: reduce over 4 n-frags + 16 cols (l15)
  #pragma unroll
  for (int m = 0; m < 8; ++m) {
    #pragma unroll
    for (int r = 0; r < 4; ++r) {
      float v = acc[m][0][r] + acc[m][1][r] + acc[m][2][r] + acc[m][3][r];
      v += __shfl_xor(v, 1); v += __shfl_xor(v, 2);
      v += __shfl_xor(v, 4); v += __shfl_xor(v, 8);
      if (l15 == 0) atomicAdd(&rowsum[Ar + RL[m] + g*4 + r], v);
    }
  }
  // col sums: reduce over 8 m-frags x 4 regs + 4 row-groups (g)
  #pragma unroll
  for (int n = 0; n < 4; ++n) {
    float v = 0.0f;
    #pragma unroll
    for (int m = 0; m < 8; ++m)
      #pragma unroll
      for (int r = 0; r < 4; ++r)
        v += acc[m][n][r];
    v += __shfl_xor(v, 16); v += __shfl_xor(v, 32);
    if (lane < 16) atomicAdd(&colsum[Br + CL[n] + l15], v);
  }
}

// ---------------- kernel 3: final scalar reduction (32 blocks, atomic) ----------------
__global__ __launch_bounds__(256) void finalize_kernel(
    const float* __restrict__ rowsum, const float* __restrict__ colsum,
    const float* __restrict__ diag, float* __restrict__ out) {
  const int i = blockIdx.x * 256 + (int)threadIdx.x;   // 32*256 == 8192 exactly
  float s = 0.5f * (logf(rowsum[i]) + logf(colsum[i])) - diag[i];
  #pragma unroll
  for (int off = 1; off < 64; off <<= 1) s += __shfl_xor(s, off);
  if ((threadIdx.x & 63) == 0) atomicAdd(out, s * (1.0f / NROWS));
}

extern "C" void kernel_launch(void* const* d_in, const int* in_sizes, int n_in,
                              void* d_out, int out_size, void* d_ws, size_t ws_size,
                              hipStream_t stream) {
  const float* x = (const float*)d_in[0];
  const float* y = (const float*)d_in[1];
  float* out = (float*)d_out;

  char* ws = (char*)d_ws;
  __bf16* Xn = (__bf16*)ws;                               // 8 MB
  __bf16* Yn = Xn + (size_t)NROWS * DDIM;                 // 8 MB
  float* rowsum = (float*)(ws + 2 * (size_t)NROWS * DDIM * sizeof(__bf16));
  float* colsum = rowsum + NROWS;
  float* diag   = colsum + NROWS;

  normalize_kernel<<<(2 * NROWS) / 4, 256, 0, stream>>>(x, y, Xn, Yn, rowsum, colsum, out);
  gemm_exp_kernel<<<dim3(NROWS / 256, NROWS / 256), 512, 0, stream>>>(
      Xn, Yn, rowsum, colsum, diag);
  finalize_kernel<<<32, 256, 0, stream>>>(rowsum, colsum, diag, out);
}

// Round 4
// 203.906 us; speedup vs baseline: 1.0012x; 1.0012x over previous
//
#include <hip/hip_runtime.h>
#include <hip/hip_bf16.h>
#include <stdint.h>

// SymmetricLoss: symmetric InfoNCE over cosine logits.
// loss = mean_i[ 0.5*(log rowsum_i + log colsum_i) - S_ii ],
// S = Xn·Ynᵀ / tau.  |S|<=2 so exp needs no max subtraction.
//
// GEMM kernel: 256x256 tile, BK=64, 8 waves, 4-phase/K-tile schedule (T3+T4)
// with counted vmcnt(6), raw s_barrier, setprio (T5), XOR-swizzled LDS via
// pre-swizzled global source (T2, rule #21). Fragment loads are volatile
// inline-asm ds_read_b128 (breaks false compiler vmcnt-ordering vs
// global_load_lds). Sync per phase = m201 template: barrier; lgkmcnt(0);
// sched_barrier(0) [rule #18 — the ONLY scheduling pin]; setprio; MFMA.

#define NROWS 8192
#define DDIM  512
#define TAU_INV 2.0f
#define KT 8            // DDIM / 64 K-tiles

typedef __bf16 bf16x8 __attribute__((ext_vector_type(8)));
typedef __bf16 bf16x4 __attribute__((ext_vector_type(4)));
typedef float  f32x4  __attribute__((ext_vector_type(4)));
typedef __attribute__((address_space(3))) const __bf16 lds_cbf16;

__device__ __forceinline__ bf16x8 ds_read8(lds_cbf16* p) {
  bf16x8 r;
  asm volatile("ds_read_b128 %0, %1" : "=v"(r) : "v"(p));
  return r;
}

// ---------------- kernel 1: row-normalize x,y -> bf16 (+ zero accumulators) ----------------
__global__ __launch_bounds__(256) void normalize_kernel(
    const float* __restrict__ x, const float* __restrict__ y,
    __bf16* __restrict__ xn, __bf16* __restrict__ yn,
    float* __restrict__ rowsum, float* __restrict__ colsum,
    float* __restrict__ out) {
  const int idx = blockIdx.x * 256 + (int)threadIdx.x;
  if (idx < NROWS) { rowsum[idx] = 0.0f; colsum[idx] = 0.0f; }
  if (idx == 0) out[0] = 0.0f;

  const int wave = threadIdx.x >> 6;
  const int lane = threadIdx.x & 63;
  const int row  = blockIdx.x * 4 + wave;   // 0..16383: first 8192 = x, rest = y
  const float* src;
  __bf16* dst;
  if (row < NROWS) { src = x + (size_t)row * DDIM;           dst = xn + (size_t)row * DDIM; }
  else             { src = y + (size_t)(row - NROWS) * DDIM; dst = yn + (size_t)(row - NROWS) * DDIM; }

  const float4* s4 = (const float4*)src;
  float4 v0 = s4[lane];
  float4 v1 = s4[lane + 64];
  float ss = v0.x*v0.x + v0.y*v0.y + v0.z*v0.z + v0.w*v0.w
           + v1.x*v1.x + v1.y*v1.y + v1.z*v1.z + v1.w*v1.w;
  #pragma unroll
  for (int off = 1; off < 64; off <<= 1) ss += __shfl_xor(ss, off);
  const float rn = 1.0f / fmaxf(sqrtf(ss), 1e-8f);

  bf16x4 o0, o1;
  o0[0]=(__bf16)(v0.x*rn); o0[1]=(__bf16)(v0.y*rn); o0[2]=(__bf16)(v0.z*rn); o0[3]=(__bf16)(v0.w*rn);
  o1[0]=(__bf16)(v1.x*rn); o1[1]=(__bf16)(v1.y*rn); o1[2]=(__bf16)(v1.z*rn); o1[3]=(__bf16)(v1.w*rn);
  *(bf16x4*)(dst + 4*lane)       = o0;
  *(bf16x4*)(dst + 256 + 4*lane) = o1;
}

// Stage one 128-row half-tile (128 x 64 bf16 = 16 KB): 2 x global_load_lds(16B)/thread.
// LDS dest linear; source column-chunk pre-swizzled cc^(r&7) (involution, rule #21).
__device__ __forceinline__ void stage_half(const __bf16* __restrict__ M,
                                           int trow0, int kt, __bf16* lds, int tid) {
  const int r0 = tid >> 3;                       // 0..63
  const int sc = (tid & 7) ^ (r0 & 7);
  const __bf16* src = M + (size_t)(trow0 + r0) * DDIM + kt * 64 + sc * 8;
  __builtin_amdgcn_global_load_lds((__attribute__((address_space(1))) void*)src,
      (__attribute__((address_space(3))) void*)(lds + tid * 8), 16, 0, 0);
  __builtin_amdgcn_global_load_lds((__attribute__((address_space(1))) void*)(src + 64 * DDIM),
      (__attribute__((address_space(3))) void*)(lds + 4096 + tid * 8), 16, 0, 0);
}

// m201-faithful phase sync: barrier; lgkm drain; ONE sched_barrier (rule #18);
// setprio around the MFMA cluster. No other pins — let the scheduler work.
#define PHASE_SYNC_PRE()  do { __builtin_amdgcn_s_barrier(); \
                               asm volatile("s_waitcnt lgkmcnt(0)" ::: "memory"); \
                               __builtin_amdgcn_sched_barrier(0); \
                               __builtin_amdgcn_s_setprio(1); } while (0)
#define PHASE_SYNC_POST() do { __builtin_amdgcn_s_setprio(0); } while (0)

// ---------------- kernel 2: fused 256^2-tile GEMM + exp + row/col sums ----------------
__global__ __launch_bounds__(512, 2) void gemm_exp_kernel(
    const __bf16* __restrict__ Xn, const __bf16* __restrict__ Yn,
    float* __restrict__ rowsum, float* __restrict__ colsum,
    float* __restrict__ diag) {
  // LDS: A bufs at 0 / 16384, B bufs at 32768 / 49152 (elems). 128 KiB total.
  __shared__ __bf16 sm[65536];

  const int tid  = threadIdx.x;
  const int lane = tid & 63;
  const int w    = tid >> 6;
  const int wr   = w >> 2;            // 0..1
  const int wc   = w & 3;             // 0..3
  const int bi = blockIdx.y, bj = blockIdx.x;

  const int l15 = lane & 15;
  const int g   = lane >> 4;          // 0..3
  const int lx  = lane & 7;
  const int sc0 = g ^ lx;             // swizzled chunk, ks=0
  const int sc1 = (4 + g) ^ lx;       // ks=1
  const int arow = wr * 64 + l15;     // + mi*16 (+128 for hi)
  const int brow = wc * 32 + l15;     // + ni*16 (+128 for hi)

  const int Ar = bi * 256;            // global row base (X)
  const int Br = bj * 256;            // global col base (Y)

  f32x4 acc[8][4] = {};

  // ---- prologue: 7 half-tiles, vmcnt 4 -> 6 ----
  stage_half(Xn, Ar,       0, sm + 0,                     tid);  // A-lo(0)
  stage_half(Yn, Br,       0, sm + 32768,                 tid);  // B-lo(0)
  stage_half(Yn, Br + 128, 0, sm + 32768 + 8192,          tid);  // B-hi(0)
  stage_half(Xn, Ar + 128, 0, sm + 8192,                  tid);  // A-hi(0)
  asm volatile("s_waitcnt vmcnt(4)" ::: "memory");
  stage_half(Xn, Ar,       1, sm + 16384,                 tid);  // A-lo(1)
  stage_half(Yn, Br,       1, sm + 32768 + 16384,         tid);  // B-lo(1)
  stage_half(Yn, Br + 128, 1, sm + 32768 + 16384 + 8192,  tid);  // B-hi(1)
  asm volatile("s_waitcnt vmcnt(6)" ::: "memory");
  __builtin_amdgcn_s_barrier();

  for (int t = 0; t < KT; ++t) {
    const int cbuf = t & 1, nbuf = cbuf ^ 1;
    lds_cbf16* As = (lds_cbf16*)(sm + cbuf * 16384);
    lds_cbf16* Bs = (lds_cbf16*)(sm + 32768 + cbuf * 16384);
    bf16x8 aq[2][4], blo[2][2], bhi[2][2];

    // ======== phase 1: acc[0..3][0..1]  (reads A-lo, B-lo) ========
    #pragma unroll
    for (int mi = 0; mi < 4; ++mi) {
      aq[0][mi] = ds_read8(As + (arow + mi*16)*64 + sc0*8);
      aq[1][mi] = ds_read8(As + (arow + mi*16)*64 + sc1*8);
    }
    #pragma unroll
    for (int ni = 0; ni < 2; ++ni) {
      blo[0][ni] = ds_read8(Bs + (brow + ni*16)*64 + sc0*8);
      blo[1][ni] = ds_read8(Bs + (brow + ni*16)*64 + sc1*8);
    }
    if (t < KT-1) stage_half(Xn, Ar + 128, t+1, sm + nbuf*16384 + 8192, tid);  // A-hi(t+1)
    PHASE_SYNC_PRE();
    #pragma unroll
    for (int mi = 0; mi < 4; ++mi)
      #pragma unroll
      for (int ni = 0; ni < 2; ++ni) {
        acc[mi][ni] = __builtin_amdgcn_mfma_f32_16x16x32_bf16(aq[0][mi], blo[0][ni], acc[mi][ni], 0,0,0);
        acc[mi][ni] = __builtin_amdgcn_mfma_f32_16x16x32_bf16(aq[1][mi], blo[1][ni], acc[mi][ni], 0,0,0);
      }
    PHASE_SYNC_POST();
    if (t == KT-1) asm volatile("s_waitcnt vmcnt(2)" ::: "memory");  // tail: B-hi(7) landed
    __builtin_amdgcn_s_barrier();

    // ======== phase 2: acc[0..3][2..3]  (reads B-hi; reuses aq) ========
    #pragma unroll
    for (int ni = 0; ni < 2; ++ni) {
      bhi[0][ni] = ds_read8(Bs + (128 + brow + ni*16)*64 + sc0*8);
      bhi[1][ni] = ds_read8(Bs + (128 + brow + ni*16)*64 + sc1*8);
    }
    if (t < KT-2) stage_half(Xn, Ar, t+2, sm + cbuf*16384, tid);               // A-lo(t+2)
    PHASE_SYNC_PRE();
    #pragma unroll
    for (int mi = 0; mi < 4; ++mi)
      #pragma unroll
      for (int ni = 0; ni < 2; ++ni) {
        acc[mi][2+ni] = __builtin_amdgcn_mfma_f32_16x16x32_bf16(aq[0][mi], bhi[0][ni], acc[mi][2+ni], 0,0,0);
        acc[mi][2+ni] = __builtin_amdgcn_mfma_f32_16x16x32_bf16(aq[1][mi], bhi[1][ni], acc[mi][2+ni], 0,0,0);
      }
    PHASE_SYNC_POST();
    if (t == KT-1) asm volatile("s_waitcnt vmcnt(0)" ::: "memory");  // tail: A-hi(7) landed
    __builtin_amdgcn_s_barrier();

    // ======== phase 3: acc[4..7][0..1]  (reads A-hi; reuses blo) ========
    #pragma unroll
    for (int mi = 0; mi < 4; ++mi) {
      aq[0][mi] = ds_read8(As + (128 + arow + mi*16)*64 + sc0*8);
      aq[1][mi] = ds_read8(As + (128 + arow + mi*16)*64 + sc1*8);
    }
    if (t < KT-2) stage_half(Yn, Br, t+2, sm + 32768 + cbuf*16384, tid);       // B-lo(t+2)
    PHASE_SYNC_PRE();
    #pragma unroll
    for (int mi = 0; mi < 4; ++mi)
      #pragma unroll
      for (int ni = 0; ni < 2; ++ni) {
        acc[4+mi][ni] = __builtin_amdgcn_mfma_f32_16x16x32_bf16(aq[0][mi], blo[0][ni], acc[4+mi][ni], 0,0,0);
        acc[4+mi][ni] = __builtin_amdgcn_mfma_f32_16x16x32_bf16(aq[1][mi], blo[1][ni], acc[4+mi][ni], 0,0,0);
      }
    PHASE_SYNC_POST();
    __builtin_amdgcn_s_barrier();

    // ======== phase 4: acc[4..7][2..3]  (no new reads) ========
    if (t < KT-2) stage_half(Yn, Br + 128, t+2, sm + 32768 + cbuf*16384 + 8192, tid); // B-hi(t+2)
    PHASE_SYNC_PRE();
    #pragma unroll
    for (int mi = 0; mi < 4; ++mi)
      #pragma unroll
      for (int ni = 0; ni < 2; ++ni) {
        acc[4+mi][2+ni] = __builtin_amdgcn_mfma_f32_16x16x32_bf16(aq[0][mi], bhi[0][ni], acc[4+mi][2+ni], 0,0,0);
        acc[4+mi][2+ni] = __builtin_amdgcn_mfma_f32_16x16x32_bf16(aq[1][mi], bhi[1][ni], acc[4+mi][2+ni], 0,0,0);
      }
    PHASE_SYNC_POST();
    // once-per-K-tile counted check: tile t+1 fully landed; 3 newest half-tiles
    // (for t+2) stay in flight (T4: never drain to 0 mid-loop).
    if (t < KT-2)       { asm volatile("s_waitcnt vmcnt(6)" ::: "memory"); }
    else if (t == KT-2) { asm volatile("s_waitcnt vmcnt(4)" ::: "memory"); }
    __builtin_amdgcn_s_barrier();
  }

  // ---------------- epilogue ----------------
  // C mapping (verified): row = frag_row_base + g*4 + reg, col = frag_col_base + l15
  int RL[8], CL[4];
  #pragma unroll
  for (int m = 0; m < 8; ++m) RL[m] = (m < 4) ? (wr*64 + m*16) : (128 + wr*64 + (m-4)*16);
  #pragma unroll
  for (int n = 0; n < 4; ++n) CL[n] = (n < 2) ? (wc*32 + n*16) : (128 + wc*32 + (n-2)*16);

  // diag (pre-exp logits), only diagonal blocks
  if (bi == bj) {
    #pragma unroll
    for (int m = 0; m < 8; ++m)
      #pragma unroll
      for (int n = 0; n < 4; ++n)
        #pragma unroll
        for (int r = 0; r < 4; ++r) {
          const int rl = RL[m] + g*4 + r, cl = CL[n] + l15;
          if (rl == cl) diag[bi*256 + rl] = TAU_INV * acc[m][n][r];
        }
  }

  // exp in place
  #pragma unroll
  for (int m = 0; m < 8; ++m)
    #pragma unroll
    for (int n = 0; n < 4; ++n)
      #pragma unroll
      for (int r = 0; r < 4; ++r)
        acc[m][n][r] = __expf(TAU_INV * acc[m][n][r]);

  // row sums: reduce over 4 n-frags + 16 cols (l15)
  #pragma unroll
  for (int m = 0; m < 8; ++m) {
    #pragma unroll
    for (int r = 0; r < 4; ++r) {
      float v = acc[m][0][r] + acc[m][1][r] + acc[m][2][r] + acc[m][3][r];
      v += __shfl_xor(v, 1); v += __shfl_xor(v, 2);
      v += __shfl_xor(v, 4); v += __shfl_xor(v, 8);
      if (l15 == 0) atomicAdd(&rowsum[Ar + RL[m] + g*4 + r], v);
    }
  }
  // col sums: reduce over 8 m-frags x 4 regs + 4 row-groups (g)
  #pragma unroll
  for (int n = 0; n < 4; ++n) {
    float v = 0.0f;
    #pragma unroll
    for (int m = 0; m < 8; ++m)
      #pragma unroll
      for (int r = 0; r < 4; ++r)
        v += acc[m][n][r];
    v += __shfl_xor(v, 16); v += __shfl_xor(v, 32);
    if (lane < 16) atomicAdd(&colsum[Br + CL[n] + l15], v);
  }
}

// ---------------- kernel 3: final scalar reduction (32 blocks, atomic) ----------------
__global__ __launch_bounds__(256) void finalize_kernel(
    const float* __restrict__ rowsum, const float* __restrict__ colsum,
    const float* __restrict__ diag, float* __restrict__ out) {
  const int i = blockIdx.x * 256 + (int)threadIdx.x;   // 32*256 == 8192 exactly
  float s = 0.5f * (logf(rowsum[i]) + logf(colsum[i])) - diag[i];
  #pragma unroll
  for (int off = 1; off < 64; off <<= 1) s += __shfl_xor(s, off);
  if ((threadIdx.x & 63) == 0) atomicAdd(out, s * (1.0f / NROWS));
}

extern "C" void kernel_launch(void* const* d_in, const int* in_sizes, int n_in,
                              void* d_out, int out_size, void* d_ws, size_t ws_size,
                              hipStream_t stream) {
  const float* x = (const float*)d_in[0];
  const float* y = (const float*)d_in[1];
  float* out = (float*)d_out;

  char* ws = (char*)d_ws;
  __bf16* Xn = (__bf16*)ws;                               // 8 MB
  __bf16* Yn = Xn + (size_t)NROWS * DDIM;                 // 8 MB
  float* rowsum = (float*)(ws + 2 * (size_t)NROWS * DDIM * sizeof(__bf16));
  float* colsum = rowsum + NROWS;
  float* diag   = colsum + NROWS;

  normalize_kernel<<<(2 * NROWS) / 4, 256, 0, stream>>>(x, y, Xn, Yn, rowsum, colsum, out);
  gemm_exp_kernel<<<dim3(NROWS / 256, NROWS / 256), 512, 0, stream>>>(
      Xn, Yn, rowsum, colsum, diag);
  finalize_kernel<<<32, 256, 0, stream>>>(rowsum, colsum, diag, out);
}

// Round 5
// 196.604 us; speedup vs baseline: 1.0384x; 1.0371x over previous
//
#include <hip/hip_runtime.h>
#include <hip/hip_bf16.h>
#include <stdint.h>

// SymmetricLoss: symmetric InfoNCE over cosine logits.
// loss = mean_i[ 0.5*(log rowsum_i + log colsum_i) - S_ii ],
// S = Xn·Ynᵀ / tau.  |S|<=2 so exp needs no max subtraction.
//
// GEMM: 256x256 tile, BK=64, 8 waves, 4-phase/K-tile (T3) with counted
// vmcnt(6) (T4), setprio (T5), XOR-swizzled LDS via pre-swizzled global
// source (T2, rule #21). Fragment loads: inline-asm ds_read_b128 using
// 4 BASE VGPRs + compile-time offset immediates (HK base+imm pattern) —
// eliminates the ~24 address VGPRs that caused R3/R4's scratch spill
// (spill vm-ops also corrupted the counted-vmcnt pipeline).

#define NROWS 8192
#define DDIM  512
#define TAU_INV 2.0f
#define KT 8            // DDIM / 64 K-tiles

typedef __bf16 bf16x8 __attribute__((ext_vector_type(8)));
typedef __bf16 bf16x4 __attribute__((ext_vector_type(4)));
typedef float  f32x4  __attribute__((ext_vector_type(4)));
typedef __attribute__((address_space(3))) const __bf16 lds_cbf16;

// ds_read_b128 from 32-bit LDS byte address + compile-time immediate offset
#define DSR(d, b, o) asm volatile("ds_read_b128 %0, %1 offset:%c2" \
                                  : "=v"(d) : "v"(b), "i"(o))

// ---------------- kernel 1: row-normalize x,y -> bf16 (+ zero accumulators) ----------------
__global__ __launch_bounds__(256) void normalize_kernel(
    const float* __restrict__ x, const float* __restrict__ y,
    __bf16* __restrict__ xn, __bf16* __restrict__ yn,
    float* __restrict__ rowsum, float* __restrict__ colsum,
    float* __restrict__ out) {
  const int idx = blockIdx.x * 256 + (int)threadIdx.x;
  if (idx < NROWS) { rowsum[idx] = 0.0f; colsum[idx] = 0.0f; }
  if (idx == 0) out[0] = 0.0f;

  const int wave = threadIdx.x >> 6;
  const int lane = threadIdx.x & 63;
  const int row  = blockIdx.x * 4 + wave;   // 0..16383: first 8192 = x, rest = y
  const float* src;
  __bf16* dst;
  if (row < NROWS) { src = x + (size_t)row * DDIM;           dst = xn + (size_t)row * DDIM; }
  else             { src = y + (size_t)(row - NROWS) * DDIM; dst = yn + (size_t)(row - NROWS) * DDIM; }

  const float4* s4 = (const float4*)src;
  float4 v0 = s4[lane];
  float4 v1 = s4[lane + 64];
  float ss = v0.x*v0.x + v0.y*v0.y + v0.z*v0.z + v0.w*v0.w
           + v1.x*v1.x + v1.y*v1.y + v1.z*v1.z + v1.w*v1.w;
  #pragma unroll
  for (int off = 1; off < 64; off <<= 1) ss += __shfl_xor(ss, off);
  const float rn = 1.0f / fmaxf(sqrtf(ss), 1e-8f);

  bf16x4 o0, o1;
  o0[0]=(__bf16)(v0.x*rn); o0[1]=(__bf16)(v0.y*rn); o0[2]=(__bf16)(v0.z*rn); o0[3]=(__bf16)(v0.w*rn);
  o1[0]=(__bf16)(v1.x*rn); o1[1]=(__bf16)(v1.y*rn); o1[2]=(__bf16)(v1.z*rn); o1[3]=(__bf16)(v1.w*rn);
  *(bf16x4*)(dst + 4*lane)       = o0;
  *(bf16x4*)(dst + 256 + 4*lane) = o1;
}

// Stage one 128-row half-tile (128 x 64 bf16 = 16 KB): 2 x global_load_lds(16B)/thread.
// LDS dest linear; source column-chunk pre-swizzled cc^(r&7) (involution, rule #21).
__device__ __forceinline__ void stage_half(const __bf16* __restrict__ M,
                                           int trow0, int kt, __bf16* lds, int tid) {
  const int r0 = tid >> 3;                       // 0..63
  const int sc = (tid & 7) ^ (r0 & 7);
  const __bf16* src = M + (size_t)(trow0 + r0) * DDIM + kt * 64 + sc * 8;
  __builtin_amdgcn_global_load_lds((__attribute__((address_space(1))) void*)src,
      (__attribute__((address_space(3))) void*)(lds + tid * 8), 16, 0, 0);
  __builtin_amdgcn_global_load_lds((__attribute__((address_space(1))) void*)(src + 64 * DDIM),
      (__attribute__((address_space(3))) void*)(lds + 4096 + tid * 8), 16, 0, 0);
}

// m201-faithful phase sync: barrier; lgkm drain; ONE sched_barrier (rule #18);
// setprio around the MFMA cluster.
#define PHASE_SYNC_PRE()  do { __builtin_amdgcn_s_barrier(); \
                               asm volatile("s_waitcnt lgkmcnt(0)" ::: "memory"); \
                               __builtin_amdgcn_sched_barrier(0); \
                               __builtin_amdgcn_s_setprio(1); } while (0)
#define PHASE_SYNC_POST() do { __builtin_amdgcn_s_setprio(0); } while (0)

// One K-tile (4 phases). CB = LDS buffer (compile-time, folded into offsets).
// STG1: stage A-hi(t+1); STG2: stage t+2 halves; W1/W2: tail vmcnt after
// phase 1/2 (-1 = none); W4: end-of-tile counted vmcnt (-1 = none).
template<int CB, bool STG1, bool STG2, int W1, int W2, int W4>
__device__ __forceinline__ void ktile(int t,
    const __bf16* __restrict__ Xn, const __bf16* __restrict__ Yn,
    int Ar, int Br, int tid, __bf16* smp,
    uint32_t aB0, uint32_t aB1, uint32_t bB0, uint32_t bB1,
    f32x4 (&acc)[8][4]) {
  constexpr int O = CB * 32768;     // buffer byte offset (A and B symmetric)
  bf16x8 aq[2][4], blo[2][2], bhi[2][2];

  // ======== phase 1: acc[0..3][0..1]  (reads A-lo, B-lo) ========
  DSR(aq[0][0], aB0, O + 0);     DSR(aq[0][1], aB0, O + 2048);
  DSR(aq[0][2], aB0, O + 4096);  DSR(aq[0][3], aB0, O + 6144);
  DSR(aq[1][0], aB1, O + 0);     DSR(aq[1][1], aB1, O + 2048);
  DSR(aq[1][2], aB1, O + 4096);  DSR(aq[1][3], aB1, O + 6144);
  DSR(blo[0][0], bB0, O + 0);    DSR(blo[0][1], bB0, O + 2048);
  DSR(blo[1][0], bB1, O + 0);    DSR(blo[1][1], bB1, O + 2048);
  if (STG1) stage_half(Xn, Ar + 128, t + 1, smp + (CB ^ 1) * 16384 + 8192, tid);
  PHASE_SYNC_PRE();
  #pragma unroll
  for (int mi = 0; mi < 4; ++mi)
    #pragma unroll
    for (int ni = 0; ni < 2; ++ni) {
      acc[mi][ni] = __builtin_amdgcn_mfma_f32_16x16x32_bf16(aq[0][mi], blo[0][ni], acc[mi][ni], 0,0,0);
      acc[mi][ni] = __builtin_amdgcn_mfma_f32_16x16x32_bf16(aq[1][mi], blo[1][ni], acc[mi][ni], 0,0,0);
    }
  PHASE_SYNC_POST();
  if constexpr (W1 >= 0) asm volatile("s_waitcnt vmcnt(%c0)" :: "i"(W1) : "memory");
  __builtin_amdgcn_s_barrier();

  // ======== phase 2: acc[0..3][2..3]  (reads B-hi; reuses aq) ========
  DSR(bhi[0][0], bB0, O + 16384);  DSR(bhi[0][1], bB0, O + 18432);
  DSR(bhi[1][0], bB1, O + 16384);  DSR(bhi[1][1], bB1, O + 18432);
  if (STG2) stage_half(Xn, Ar, t + 2, smp + CB * 16384, tid);
  PHASE_SYNC_PRE();
  #pragma unroll
  for (int mi = 0; mi < 4; ++mi)
    #pragma unroll
    for (int ni = 0; ni < 2; ++ni) {
      acc[mi][2+ni] = __builtin_amdgcn_mfma_f32_16x16x32_bf16(aq[0][mi], bhi[0][ni], acc[mi][2+ni], 0,0,0);
      acc[mi][2+ni] = __builtin_amdgcn_mfma_f32_16x16x32_bf16(aq[1][mi], bhi[1][ni], acc[mi][2+ni], 0,0,0);
    }
  PHASE_SYNC_POST();
  if constexpr (W2 >= 0) asm volatile("s_waitcnt vmcnt(%c0)" :: "i"(W2) : "memory");
  __builtin_amdgcn_s_barrier();

  // ======== phase 3: acc[4..7][0..1]  (reads A-hi into aq; reuses blo) ========
  DSR(aq[0][0], aB0, O + 16384);  DSR(aq[0][1], aB0, O + 18432);
  DSR(aq[0][2], aB0, O + 20480);  DSR(aq[0][3], aB0, O + 22528);
  DSR(aq[1][0], aB1, O + 16384);  DSR(aq[1][1], aB1, O + 18432);
  DSR(aq[1][2], aB1, O + 20480);  DSR(aq[1][3], aB1, O + 22528);
  if (STG2) stage_half(Yn, Br, t + 2, smp + 32768 + CB * 16384, tid);
  PHASE_SYNC_PRE();
  #pragma unroll
  for (int mi = 0; mi < 4; ++mi)
    #pragma unroll
    for (int ni = 0; ni < 2; ++ni) {
      acc[4+mi][ni] = __builtin_amdgcn_mfma_f32_16x16x32_bf16(aq[0][mi], blo[0][ni], acc[4+mi][ni], 0,0,0);
      acc[4+mi][ni] = __builtin_amdgcn_mfma_f32_16x16x32_bf16(aq[1][mi], blo[1][ni], acc[4+mi][ni], 0,0,0);
    }
  PHASE_SYNC_POST();
  __builtin_amdgcn_s_barrier();

  // ======== phase 4: acc[4..7][2..3]  (no new reads) ========
  if (STG2) stage_half(Yn, Br + 128, t + 2, smp + 32768 + CB * 16384 + 8192, tid);
  PHASE_SYNC_PRE();
  #pragma unroll
  for (int mi = 0; mi < 4; ++mi)
    #pragma unroll
    for (int ni = 0; ni < 2; ++ni) {
      acc[4+mi][2+ni] = __builtin_amdgcn_mfma_f32_16x16x32_bf16(aq[0][mi], bhi[0][ni], acc[4+mi][2+ni], 0,0,0);
      acc[4+mi][2+ni] = __builtin_amdgcn_mfma_f32_16x16x32_bf16(aq[1][mi], bhi[1][ni], acc[4+mi][2+ni], 0,0,0);
    }
  PHASE_SYNC_POST();
  // counted check: tile t+1 fully landed; 3 newest half-tiles (t+2) in flight.
  if constexpr (W4 >= 0) asm volatile("s_waitcnt vmcnt(%c0)" :: "i"(W4) : "memory");
  __builtin_amdgcn_s_barrier();
}

// ---------------- kernel 2: fused 256^2-tile GEMM + exp + row/col sums ----------------
__global__ __launch_bounds__(512, 2) void gemm_exp_kernel(
    const __bf16* __restrict__ Xn, const __bf16* __restrict__ Yn,
    float* __restrict__ rowsum, float* __restrict__ colsum,
    float* __restrict__ diag) {
  // LDS: A bufs at 0 / 16384, B bufs at 32768 / 49152 (elems). 128 KiB total.
  __shared__ __bf16 sm[65536];

  const int tid  = threadIdx.x;
  const int lane = tid & 63;
  const int w    = tid >> 6;
  const int wr   = w >> 2;            // 0..1
  const int wc   = w & 3;             // 0..3
  const int bi = blockIdx.y, bj = blockIdx.x;

  const int l15 = lane & 15;
  const int g   = lane >> 4;          // 0..3
  const int lx  = lane & 7;
  const int Ar = bi * 256;            // global row base (X)
  const int Br = bj * 256;            // global col base (Y)

  // 4 LDS base-address VGPRs; all other addressing via offset immediates.
  // A byte addr = row*128 + sc*16, row = wr*64 + l15 (+mi*16/+128 via imm),
  // sc(ks) = (ks*4 + g) ^ lx  ->  sc1*16 = (sc0*16) ^ 64.
  const uint32_t ldsb = (uint32_t)(uintptr_t)(lds_cbf16*)sm;
  const uint32_t aB0 = ldsb + (uint32_t)(((wr * 64 + l15) * 64 + (g ^ lx) * 8) * 2);
  const uint32_t aB1 = aB0 ^ 64u;
  const uint32_t bB0 = ldsb + 65536u + (uint32_t)(((wc * 32 + l15) * 64 + (g ^ lx) * 8) * 2);
  const uint32_t bB1 = bB0 ^ 64u;

  f32x4 acc[8][4] = {};

  // ---- prologue: 7 half-tiles, vmcnt 4 -> 6 ----
  stage_half(Xn, Ar,       0, sm + 0,                     tid);  // A-lo(0)
  stage_half(Yn, Br,       0, sm + 32768,                 tid);  // B-lo(0)
  stage_half(Yn, Br + 128, 0, sm + 32768 + 8192,          tid);  // B-hi(0)
  stage_half(Xn, Ar + 128, 0, sm + 8192,                  tid);  // A-hi(0)
  asm volatile("s_waitcnt vmcnt(4)" ::: "memory");
  stage_half(Xn, Ar,       1, sm + 16384,                 tid);  // A-lo(1)
  stage_half(Yn, Br,       1, sm + 32768 + 16384,         tid);  // B-lo(1)
  stage_half(Yn, Br + 128, 1, sm + 32768 + 16384 + 8192,  tid);  // B-hi(1)
  asm volatile("s_waitcnt vmcnt(6)" ::: "memory");
  __builtin_amdgcn_s_barrier();

  // ---- K loop: tiles 0..5 steady (vmcnt 6), 6 ramp-down (4), 7 drain ----
  #pragma unroll 1
  for (int tt = 0; tt < 3; ++tt) {
    ktile<0, true, true, -1, -1, 6>(2*tt,     Xn, Yn, Ar, Br, tid, sm, aB0, aB1, bB0, bB1, acc);
    ktile<1, true, true, -1, -1, 6>(2*tt + 1, Xn, Yn, Ar, Br, tid, sm, aB0, aB1, bB0, bB1, acc);
  }
  ktile<0, true,  false, -1, -1, 4>(6, Xn, Yn, Ar, Br, tid, sm, aB0, aB1, bB0, bB1, acc);
  ktile<1, false, false,  2,  0, -1>(7, Xn, Yn, Ar, Br, tid, sm, aB0, aB1, bB0, bB1, acc);

  // ---------------- epilogue ----------------
  // C mapping (verified): row = frag_row_base + g*4 + reg, col = frag_col_base + l15
  int RL[8], CL[4];
  #pragma unroll
  for (int m = 0; m < 8; ++m) RL[m] = (m < 4) ? (wr*64 + m*16) : (128 + wr*64 + (m-4)*16);
  #pragma unroll
  for (int n = 0; n < 4; ++n) CL[n] = (n < 2) ? (wc*32 + n*16) : (128 + wc*32 + (n-2)*16);

  // diag (pre-exp logits), only diagonal blocks
  if (bi == bj) {
    #pragma unroll
    for (int m = 0; m < 8; ++m)
      #pragma unroll
      for (int n = 0; n < 4; ++n)
        #pragma unroll
        for (int r = 0; r < 4; ++r) {
          const int rl = RL[m] + g*4 + r, cl = CL[n] + l15;
          if (rl == cl) diag[bi*256 + rl] = TAU_INV * acc[m][n][r];
        }
  }

  // exp in place
  #pragma unroll
  for (int m = 0; m < 8; ++m)
    #pragma unroll
    for (int n = 0; n < 4; ++n)
      #pragma unroll
      for (int r = 0; r < 4; ++r)
        acc[m][n][r] = __expf(TAU_INV * acc[m][n][r]);

  // row sums: reduce over 4 n-frags + 16 cols (l15)
  #pragma unroll
  for (int m = 0; m < 8; ++m) {
    #pragma unroll
    for (int r = 0; r < 4; ++r) {
      float v = acc[m][0][r] + acc[m][1][r] + acc[m][2][r] + acc[m][3][r];
      v += __shfl_xor(v, 1); v += __shfl_xor(v, 2);
      v += __shfl_xor(v, 4); v += __shfl_xor(v, 8);
      if (l15 == 0) atomicAdd(&rowsum[Ar + RL[m] + g*4 + r], v);
    }
  }
  // col sums: reduce over 8 m-frags x 4 regs + 4 row-groups (g)
  #pragma unroll
  for (int n = 0; n < 4; ++n) {
    float v = 0.0f;
    #pragma unroll
    for (int m = 0; m < 8; ++m)
      #pragma unroll
      for (int r = 0; r < 4; ++r)
        v += acc[m][n][r];
    v += __shfl_xor(v, 16); v += __shfl_xor(v, 32);
    if (lane < 16) atomicAdd(&colsum[Br + CL[n] + l15], v);
  }
}

// ---------------- kernel 3: final scalar reduction (32 blocks, atomic) ----------------
__global__ __launch_bounds__(256) void finalize_kernel(
    const float* __restrict__ rowsum, const float* __restrict__ colsum,
    const float* __restrict__ diag, float* __restrict__ out) {
  const int i = blockIdx.x * 256 + (int)threadIdx.x;   // 32*256 == 8192 exactly
  float s = 0.5f * (logf(rowsum[i]) + logf(colsum[i])) - diag[i];
  #pragma unroll
  for (int off = 1; off < 64; off <<= 1) s += __shfl_xor(s, off);
  if ((threadIdx.x & 63) == 0) atomicAdd(out, s * (1.0f / NROWS));
}

extern "C" void kernel_launch(void* const* d_in, const int* in_sizes, int n_in,
                              void* d_out, int out_size, void* d_ws, size_t ws_size,
                              hipStream_t stream) {
  const float* x = (const float*)d_in[0];
  const float* y = (const float*)d_in[1];
  float* out = (float*)d_out;

  char* ws = (char*)d_ws;
  __bf16* Xn = (__bf16*)ws;                               // 8 MB
  __bf16* Yn = Xn + (size_t)NROWS * DDIM;                 // 8 MB
  float* rowsum = (float*)(ws + 2 * (size_t)NROWS * DDIM * sizeof(__bf16));
  float* colsum = rowsum + NROWS;
  float* diag   = colsum + NROWS;

  normalize_kernel<<<(2 * NROWS) / 4, 256, 0, stream>>>(x, y, Xn, Yn, rowsum, colsum, out);
  gemm_exp_kernel<<<dim3(NROWS / 256, NROWS / 256), 512, 0, stream>>>(
      Xn, Yn, rowsum, colsum, diag);
  finalize_kernel<<<32, 256, 0, stream>>>(rowsum, colsum, diag, out);
}

// Round 6
// 182.596 us; speedup vs baseline: 1.1181x; 1.0767x over previous
//
#include <hip/hip_runtime.h>
#include <hip/hip_bf16.h>
#include <stdint.h>

// SymmetricLoss: symmetric InfoNCE over cosine logits.
// loss = mean_i[ 0.5*(log rowsum_i + log colsum_i) - S_ii ],
// S = Xn·Ynᵀ / tau.  |S|<=2 so exp needs no max subtraction.
//
// GEMM: 128x256 tile, BK=64, 8 waves (2Mx4N, 64x64/wave), ONE barrier per
// K-tile, fragment ds_reads software-pipelined ONE K-TILE AHEAD into
// double-banked registers so LDS latency and stage latency complete under
// the MFMA cluster (fixes R2-R5's 22% MfmaUtil lockstep stall).
// T1 XCD swizzle, T2 XOR-swizzled LDS via pre-swizzled global source
// (rule #21), counted-wait discipline: end-of-body vmcnt(0)/lgkmcnt(0)
// are ~free (ops issued ~500+ cyc earlier). All hazards deterministic:
//   RAW reads(t) vs stage(t):   prev body vmcnt(0)+barrier
//   WAR stage(t+1) vs reads(t-1): prev body lgkmcnt(0)+barrier

#define NROWS 8192
#define DDIM  512
#define TAU_INV 2.0f

typedef __bf16 bf16x8 __attribute__((ext_vector_type(8)));
typedef __bf16 bf16x4 __attribute__((ext_vector_type(4)));
typedef float  f32x4  __attribute__((ext_vector_type(4)));
typedef __attribute__((address_space(3))) const __bf16 lds_cbf16;

// ds_read_b128 from 32-bit LDS byte address + compile-time immediate offset
#define DSR(d, b, o) asm volatile("ds_read_b128 %0, %1 offset:%c2" \
                                  : "=v"(d) : "v"(b), "i"(o))

__device__ __forceinline__ void gload(const __bf16* src, __bf16* dst) {
  __builtin_amdgcn_global_load_lds((__attribute__((address_space(1))) void*)src,
      (__attribute__((address_space(3))) void*)dst, 16, 0, 0);
}

// ---------------- kernel 1: row-normalize x,y -> bf16 (+ zero accumulators) ----------------
__global__ __launch_bounds__(256) void normalize_kernel(
    const float* __restrict__ x, const float* __restrict__ y,
    __bf16* __restrict__ xn, __bf16* __restrict__ yn,
    float* __restrict__ rowsum, float* __restrict__ colsum,
    float* __restrict__ out) {
  const int idx = blockIdx.x * 256 + (int)threadIdx.x;
  if (idx < NROWS) { rowsum[idx] = 0.0f; colsum[idx] = 0.0f; }
  if (idx == 0) out[0] = 0.0f;

  const int wave = threadIdx.x >> 6;
  const int lane = threadIdx.x & 63;
  const int row  = blockIdx.x * 4 + wave;   // 0..16383: first 8192 = x, rest = y
  const float* src;
  __bf16* dst;
  if (row < NROWS) { src = x + (size_t)row * DDIM;           dst = xn + (size_t)row * DDIM; }
  else             { src = y + (size_t)(row - NROWS) * DDIM; dst = yn + (size_t)(row - NROWS) * DDIM; }

  const float4* s4 = (const float4*)src;
  float4 v0 = s4[lane];
  float4 v1 = s4[lane + 64];
  float ss = v0.x*v0.x + v0.y*v0.y + v0.z*v0.z + v0.w*v0.w
           + v1.x*v1.x + v1.y*v1.y + v1.z*v1.z + v1.w*v1.w;
  #pragma unroll
  for (int off = 1; off < 64; off <<= 1) ss += __shfl_xor(ss, off);
  const float rn = 1.0f / fmaxf(sqrtf(ss), 1e-8f);

  bf16x4 o0, o1;
  o0[0]=(__bf16)(v0.x*rn); o0[1]=(__bf16)(v0.y*rn); o0[2]=(__bf16)(v0.z*rn); o0[3]=(__bf16)(v0.w*rn);
  o1[0]=(__bf16)(v1.x*rn); o1[1]=(__bf16)(v1.y*rn); o1[2]=(__bf16)(v1.z*rn); o1[3]=(__bf16)(v1.w*rn);
  *(bf16x4*)(dst + 4*lane)       = o0;
  *(bf16x4*)(dst + 256 + 4*lane) = o1;
}

// ---------------- GEMM body: one K-tile, software-pipelined by 1 ----------------
// LDS (bytes): A bufs [0,16K)+[16K,32K); B bufs [32K,64K)+[64K,96K). 96 KiB.
// Stage: A tile 16KB = 2 gload/thread, B tile 32KB = 4 gload/thread.
// Source column-chunk pre-swizzled cc^(r&7) (involution, rule #21).
template<int T>
__device__ __forceinline__ void body(
    const __bf16* __restrict__ PA, const __bf16* __restrict__ PB,
    __bf16* __restrict__ sm, int tid,
    uint32_t arB0, uint32_t arB1, uint32_t brB0, uint32_t brB1,
    bf16x8 (&aB)[2][8], bf16x8 (&bB)[2][8], f32x4 (&acc)[4][4]) {
  // ---- stage K-tile T+1 into the opposite buffer ----
  if constexpr (T <= 6) {
    constexpr int S = T + 1, bufS = S & 1;
    const __bf16* pa = PA + S * 64;
    gload(pa,          sm + bufS*8192 + tid*8);
    gload(pa + 32768,  sm + bufS*8192 + 4096 + tid*8);
    const __bf16* pb = PB + S * 64;
    gload(pb,          sm + 16384 + bufS*16384 + tid*8);
    gload(pb + 32768,  sm + 16384 + bufS*16384 + 4096  + tid*8);
    gload(pb + 65536,  sm + 16384 + bufS*16384 + 8192  + tid*8);
    gload(pb + 98304,  sm + 16384 + bufS*16384 + 12288 + tid*8);
  }
  // ---- ds_read K-tile T fragments into bank T&1 (consumed next body) ----
  {
    constexpr int bk = T & 1, AO = bk * 16384, BO = bk * 32768;
    DSR(aB[bk][0], arB0, AO + 0);    DSR(aB[bk][1], arB1, AO + 0);
    DSR(aB[bk][2], arB0, AO + 2048); DSR(aB[bk][3], arB1, AO + 2048);
    DSR(aB[bk][4], arB0, AO + 4096); DSR(aB[bk][5], arB1, AO + 4096);
    DSR(aB[bk][6], arB0, AO + 6144); DSR(aB[bk][7], arB1, AO + 6144);
    DSR(bB[bk][0], brB0, BO + 0);    DSR(bB[bk][1], brB1, BO + 0);
    DSR(bB[bk][2], brB0, BO + 2048); DSR(bB[bk][3], brB1, BO + 2048);
    DSR(bB[bk][4], brB0, BO + 4096); DSR(bB[bk][5], brB1, BO + 4096);
    DSR(bB[bk][6], brB0, BO + 6144); DSR(bB[bk][7], brB1, BO + 6144);
  }
  __builtin_amdgcn_sched_barrier(0);   // keep issue order: loads first, MFMA after
  // ---- MFMA for K-tile T-1 (operands certified by prev body's waits+barrier) ----
  if constexpr (T >= 1) {
    constexpr int pb2 = (T - 1) & 1;
    __builtin_amdgcn_s_setprio(1);
    #pragma unroll
    for (int mi = 0; mi < 4; ++mi)
      #pragma unroll
      for (int ni = 0; ni < 4; ++ni) {
        acc[mi][ni] = __builtin_amdgcn_mfma_f32_16x16x32_bf16(aB[pb2][mi*2+0], bB[pb2][ni*2+0], acc[mi][ni], 0,0,0);
        acc[mi][ni] = __builtin_amdgcn_mfma_f32_16x16x32_bf16(aB[pb2][mi*2+1], bB[pb2][ni*2+1], acc[mi][ni], 0,0,0);
      }
    __builtin_amdgcn_s_setprio(0);
  }
  // ---- certify: stage(T+1) landed, reads(T) landed (both issued ~500+ cyc ago) ----
  asm volatile("s_waitcnt vmcnt(0) lgkmcnt(0)" ::: "memory");
  __builtin_amdgcn_s_barrier();
  __builtin_amdgcn_sched_barrier(0);   // nothing crosses the body boundary
}

// ---------------- kernel 2: fused 128x256-tile GEMM + exp + row/col sums ----------------
__global__ __launch_bounds__(512, 2) void gemm_exp_kernel(
    const __bf16* __restrict__ Xn, const __bf16* __restrict__ Yn,
    float* __restrict__ rowsum, float* __restrict__ colsum,
    float* __restrict__ diag) {
  __shared__ __bf16 sm[49152];   // 96 KiB

  const int tid  = threadIdx.x;
  const int lane = tid & 63;
  const int w    = tid >> 6;
  const int wr   = w >> 2;            // 0..1  (64-row half)
  const int wc   = w & 3;             // 0..3  (64-col quarter)

  // XCD-aware swizzle (T1): 2048 blocks, 8 XCDs, bi-fast so each XCD's
  // chunk shares 4 B-panels (1 MB, L2-resident).
  const int id  = blockIdx.x;
  const int swz = (id & 7) * 256 + (id >> 3);
  const int bi  = swz & 63;           // 64 row tiles of 128
  const int bj  = swz >> 6;           // 32 col tiles of 256
  const int Ar = bi * 128;
  const int Br = bj * 256;

  const int l15 = lane & 15;
  const int g   = lane >> 4;          // 0..3
  const int sw  = g ^ (l15 & 7);      // swizzled chunk, ks=0

  // per-thread staging pointers (include source pre-swizzle)
  const int r0  = tid >> 3;
  const int sc0 = (tid & 7) ^ (r0 & 7);
  const __bf16* PA = Xn + (size_t)(Ar + r0) * DDIM + sc0 * 8;
  const __bf16* PB = Yn + (size_t)(Br + r0) * DDIM + sc0 * 8;

  // LDS read base regs (byte addrs); ks=1 -> ^64
  const uint32_t ldsb = (uint32_t)(uintptr_t)(lds_cbf16*)sm;
  const uint32_t arB0 = ldsb + (uint32_t)((wr*64 + l15)*128 + sw*16);
  const uint32_t arB1 = arB0 ^ 64u;
  const uint32_t brB0 = ldsb + 32768u + (uint32_t)((wc*64 + l15)*128 + sw*16);
  const uint32_t brB1 = brB0 ^ 64u;

  bf16x8 aB[2][8], bB[2][8];
  f32x4 acc[4][4] = {};

  // ---- prologue: stage K-tile 0, full drain, barrier ----
  gload(PA,          sm + tid*8);
  gload(PA + 32768,  sm + 4096 + tid*8);
  gload(PB,          sm + 16384 + tid*8);
  gload(PB + 32768,  sm + 16384 + 4096  + tid*8);
  gload(PB + 65536,  sm + 16384 + 8192  + tid*8);
  gload(PB + 98304,  sm + 16384 + 12288 + tid*8);
  asm volatile("s_waitcnt vmcnt(0)" ::: "memory");
  __builtin_amdgcn_s_barrier();
  __builtin_amdgcn_sched_barrier(0);

  // ---- 8 K-tiles, MFMA trailing by one ----
  body<0>(PA, PB, sm, tid, arB0, arB1, brB0, brB1, aB, bB, acc);
  body<1>(PA, PB, sm, tid, arB0, arB1, brB0, brB1, aB, bB, acc);
  body<2>(PA, PB, sm, tid, arB0, arB1, brB0, brB1, aB, bB, acc);
  body<3>(PA, PB, sm, tid, arB0, arB1, brB0, brB1, aB, bB, acc);
  body<4>(PA, PB, sm, tid, arB0, arB1, brB0, brB1, aB, bB, acc);
  body<5>(PA, PB, sm, tid, arB0, arB1, brB0, brB1, aB, bB, acc);
  body<6>(PA, PB, sm, tid, arB0, arB1, brB0, brB1, aB, bB, acc);
  body<7>(PA, PB, sm, tid, arB0, arB1, brB0, brB1, aB, bB, acc);
  // tail: MFMA for K-tile 7 (bank 1)
  __builtin_amdgcn_s_setprio(1);
  #pragma unroll
  for (int mi = 0; mi < 4; ++mi)
    #pragma unroll
    for (int ni = 0; ni < 4; ++ni) {
      acc[mi][ni] = __builtin_amdgcn_mfma_f32_16x16x32_bf16(aB[1][mi*2+0], bB[1][ni*2+0], acc[mi][ni], 0,0,0);
      acc[mi][ni] = __builtin_amdgcn_mfma_f32_16x16x32_bf16(aB[1][mi*2+1], bB[1][ni*2+1], acc[mi][ni], 0,0,0);
    }
  __builtin_amdgcn_s_setprio(0);

  // ---------------- epilogue ----------------
  // C mapping (verified): row = RL[mi] + g*4 + r, col = CL[ni] + l15
  int RL[4], CL[4];
  #pragma unroll
  for (int m = 0; m < 4; ++m) RL[m] = wr*64 + m*16;
  #pragma unroll
  for (int n = 0; n < 4; ++n) CL[n] = wc*64 + n*16;

  // diag (pre-exp logits): tile contains diagonal iff bj == bi>>1
  if ((bi >> 1) == bj) {
    #pragma unroll
    for (int m = 0; m < 4; ++m)
      #pragma unroll
      for (int n = 0; n < 4; ++n)
        #pragma unroll
        for (int r = 0; r < 4; ++r) {
          const int grow = Ar + RL[m] + g*4 + r, gcol = Br + CL[n] + l15;
          if (grow == gcol) diag[grow] = TAU_INV * acc[m][n][r];
        }
  }

  // exp in place
  #pragma unroll
  for (int m = 0; m < 4; ++m)
    #pragma unroll
    for (int n = 0; n < 4; ++n)
      #pragma unroll
      for (int r = 0; r < 4; ++r)
        acc[m][n][r] = __expf(TAU_INV * acc[m][n][r]);

  // row sums: reduce over 4 n-frags + 16 cols (l15)
  #pragma unroll
  for (int m = 0; m < 4; ++m) {
    #pragma unroll
    for (int r = 0; r < 4; ++r) {
      float v = acc[m][0][r] + acc[m][1][r] + acc[m][2][r] + acc[m][3][r];
      v += __shfl_xor(v, 1); v += __shfl_xor(v, 2);
      v += __shfl_xor(v, 4); v += __shfl_xor(v, 8);
      if (l15 == 0) atomicAdd(&rowsum[Ar + RL[m] + g*4 + r], v);
    }
  }
  // col sums: reduce over 4 m-frags x 4 regs + 4 row-groups (g)
  #pragma unroll
  for (int n = 0; n < 4; ++n) {
    float v = 0.0f;
    #pragma unroll
    for (int m = 0; m < 4; ++m)
      #pragma unroll
      for (int r = 0; r < 4; ++r)
        v += acc[m][n][r];
    v += __shfl_xor(v, 16); v += __shfl_xor(v, 32);
    if (lane < 16) atomicAdd(&colsum[Br + CL[n] + l15], v);
  }
}

// ---------------- kernel 3: final scalar reduction (32 blocks, atomic) ----------------
__global__ __launch_bounds__(256) void finalize_kernel(
    const float* __restrict__ rowsum, const float* __restrict__ colsum,
    const float* __restrict__ diag, float* __restrict__ out) {
  const int i = blockIdx.x * 256 + (int)threadIdx.x;   // 32*256 == 8192 exactly
  float s = 0.5f * (logf(rowsum[i]) + logf(colsum[i])) - diag[i];
  #pragma unroll
  for (int off = 1; off < 64; off <<= 1) s += __shfl_xor(s, off);
  if ((threadIdx.x & 63) == 0) atomicAdd(out, s * (1.0f / NROWS));
}

extern "C" void kernel_launch(void* const* d_in, const int* in_sizes, int n_in,
                              void* d_out, int out_size, void* d_ws, size_t ws_size,
                              hipStream_t stream) {
  const float* x = (const float*)d_in[0];
  const float* y = (const float*)d_in[1];
  float* out = (float*)d_out;

  char* ws = (char*)d_ws;
  __bf16* Xn = (__bf16*)ws;                               // 8 MB
  __bf16* Yn = Xn + (size_t)NROWS * DDIM;                 // 8 MB
  float* rowsum = (float*)(ws + 2 * (size_t)NROWS * DDIM * sizeof(__bf16));
  float* colsum = rowsum + NROWS;
  float* diag   = colsum + NROWS;

  normalize_kernel<<<(2 * NROWS) / 4, 256, 0, stream>>>(x, y, Xn, Yn, rowsum, colsum, out);
  gemm_exp_kernel<<<2048, 512, 0, stream>>>(Xn, Yn, rowsum, colsum, diag);
  finalize_kernel<<<32, 256, 0, stream>>>(rowsum, colsum, diag, out);
}

// Round 7
// 178.592 us; speedup vs baseline: 1.1431x; 1.0224x over previous
//
#include <hip/hip_runtime.h>
#include <hip/hip_bf16.h>
#include <stdint.h>

// SymmetricLoss: symmetric InfoNCE over cosine logits.
// loss = mean_i[ 0.5*(log rowsum_i + log colsum_i) - S_ii ],
// S = Xn·Ynᵀ / tau.  |S|<=2 so exp needs no max subtraction.
//
// GEMM: 128x256 tile, BK=64, 8 waves (2Mx4N, 64x64/wave), ONE barrier per
// K-tile. Fragment ds_reads pipelined 1 K-tile ahead (double-banked regs);
// global->LDS staging pipelined TWO K-tiles ahead through a 3-buffer LDS
// rotation (144 KiB) with counted vmcnt(6) — the needed tile's loads are
// waited ~2 body-times after issue, so stage latency (L3/HBM) is fully
// hidden (fixes R6's exposed ~300-600 cyc/tile).
// Hazards (deterministic):
//   RAW read(T) vs stage(T):        body T-1's vmcnt(6) + barrier
//   WAR stage(T+2) vs read(T-1):    body T-1's lgkmcnt(0) + barrier
//     (buffer (T+2)%3 == buffer (T-1)%3)

#define NROWS 8192
#define DDIM  512
#define TAU_INV 2.0f

typedef __bf16 bf16x8 __attribute__((ext_vector_type(8)));
typedef __bf16 bf16x4 __attribute__((ext_vector_type(4)));
typedef float  f32x4  __attribute__((ext_vector_type(4)));
typedef __attribute__((address_space(3))) const __bf16 lds_cbf16;

// ds_read_b128 from 32-bit LDS byte address + compile-time immediate offset
#define DSR(d, b, o) asm volatile("ds_read_b128 %0, %1 offset:%c2" \
                                  : "=v"(d) : "v"(b), "i"(o))

__device__ __forceinline__ void gload(const __bf16* src, __bf16* dst) {
  __builtin_amdgcn_global_load_lds((__attribute__((address_space(1))) void*)src,
      (__attribute__((address_space(3))) void*)dst, 16, 0, 0);
}

// ---------------- kernel 1: row-normalize x,y -> bf16 (+ zero accumulators) ----------------
__global__ __launch_bounds__(256) void normalize_kernel(
    const float* __restrict__ x, const float* __restrict__ y,
    __bf16* __restrict__ xn, __bf16* __restrict__ yn,
    float* __restrict__ rowsum, float* __restrict__ colsum,
    float* __restrict__ out) {
  const int idx = blockIdx.x * 256 + (int)threadIdx.x;
  if (idx < NROWS) { rowsum[idx] = 0.0f; colsum[idx] = 0.0f; }
  if (idx == 0) out[0] = 0.0f;

  const int wave = threadIdx.x >> 6;
  const int lane = threadIdx.x & 63;
  const int row  = blockIdx.x * 4 + wave;   // 0..16383: first 8192 = x, rest = y
  const float* src;
  __bf16* dst;
  if (row < NROWS) { src = x + (size_t)row * DDIM;           dst = xn + (size_t)row * DDIM; }
  else             { src = y + (size_t)(row - NROWS) * DDIM; dst = yn + (size_t)(row - NROWS) * DDIM; }

  const float4* s4 = (const float4*)src;
  float4 v0 = s4[lane];
  float4 v1 = s4[lane + 64];
  float ss = v0.x*v0.x + v0.y*v0.y + v0.z*v0.z + v0.w*v0.w
           + v1.x*v1.x + v1.y*v1.y + v1.z*v1.z + v1.w*v1.w;
  #pragma unroll
  for (int off = 1; off < 64; off <<= 1) ss += __shfl_xor(ss, off);
  const float rn = 1.0f / fmaxf(sqrtf(ss), 1e-8f);

  bf16x4 o0, o1;
  o0[0]=(__bf16)(v0.x*rn); o0[1]=(__bf16)(v0.y*rn); o0[2]=(__bf16)(v0.z*rn); o0[3]=(__bf16)(v0.w*rn);
  o1[0]=(__bf16)(v1.x*rn); o1[1]=(__bf16)(v1.y*rn); o1[2]=(__bf16)(v1.z*rn); o1[3]=(__bf16)(v1.w*rn);
  *(bf16x4*)(dst + 4*lane)       = o0;
  *(bf16x4*)(dst + 256 + 4*lane) = o1;
}

// ---------------- GEMM staging: stage K-tile S into LDS buffer S%3 ----------------
// LDS elems: A bufs 3 x 8192 at [0,24576); B bufs 3 x 16384 at [24576,73728).
// 144 KiB total. Source column-chunk pre-swizzled (rule #21 involution).
template<int S>
__device__ __forceinline__ void stage(
    const __bf16* __restrict__ PA, const __bf16* __restrict__ PB,
    __bf16* __restrict__ sm, int tid) {
  constexpr int buf = S % 3;
  const __bf16* pa = PA + S * 64;
  gload(pa,          sm + buf*8192 + tid*8);
  gload(pa + 32768,  sm + buf*8192 + 4096 + tid*8);
  const __bf16* pb = PB + S * 64;
  gload(pb,          sm + 24576 + buf*16384 + tid*8);
  gload(pb + 32768,  sm + 24576 + buf*16384 + 4096  + tid*8);
  gload(pb + 65536,  sm + 24576 + buf*16384 + 8192  + tid*8);
  gload(pb + 98304,  sm + 24576 + buf*16384 + 12288 + tid*8);
}

// ---------------- GEMM body: one K-tile ----------------
template<int T>
__device__ __forceinline__ void body(
    const __bf16* __restrict__ PA, const __bf16* __restrict__ PB,
    __bf16* __restrict__ sm, int tid,
    const uint32_t (&aB0)[3], const uint32_t (&aB1)[3],
    const uint32_t (&bB0)[3], const uint32_t (&bB1)[3],
    bf16x8 (&aB)[2][8], bf16x8 (&bB)[2][8], f32x4 (&acc)[4][4]) {
  // ---- stage K-tile T+2 into buffer (T+2)%3 ----
  if constexpr (T <= 5) stage<T + 2>(PA, PB, sm, tid);
  // ---- ds_read K-tile T fragments (buffer T%3) into bank T&1 ----
  {
    constexpr int rb = T % 3, bk = T & 1;
    DSR(aB[bk][0], aB0[rb], 0);    DSR(aB[bk][1], aB1[rb], 0);
    DSR(aB[bk][2], aB0[rb], 2048); DSR(aB[bk][3], aB1[rb], 2048);
    DSR(aB[bk][4], aB0[rb], 4096); DSR(aB[bk][5], aB1[rb], 4096);
    DSR(aB[bk][6], aB0[rb], 6144); DSR(aB[bk][7], aB1[rb], 6144);
    DSR(bB[bk][0], bB0[rb], 0);    DSR(bB[bk][1], bB1[rb], 0);
    DSR(bB[bk][2], bB0[rb], 2048); DSR(bB[bk][3], bB1[rb], 2048);
    DSR(bB[bk][4], bB0[rb], 4096); DSR(bB[bk][5], bB1[rb], 4096);
    DSR(bB[bk][6], bB0[rb], 6144); DSR(bB[bk][7], bB1[rb], 6144);
  }
  __builtin_amdgcn_sched_barrier(0);   // loads first, MFMA after
  // ---- MFMA for K-tile T-1 (operands certified by prev body's waits+barrier) ----
  if constexpr (T >= 1) {
    constexpr int pb2 = (T - 1) & 1;
    __builtin_amdgcn_s_setprio(1);
    #pragma unroll
    for (int mi = 0; mi < 4; ++mi)
      #pragma unroll
      for (int ni = 0; ni < 4; ++ni) {
        acc[mi][ni] = __builtin_amdgcn_mfma_f32_16x16x32_bf16(aB[pb2][mi*2+0], bB[pb2][ni*2+0], acc[mi][ni], 0,0,0);
        acc[mi][ni] = __builtin_amdgcn_mfma_f32_16x16x32_bf16(aB[pb2][mi*2+1], bB[pb2][ni*2+1], acc[mi][ni], 0,0,0);
      }
    __builtin_amdgcn_s_setprio(0);
  }
  // ---- waits: stage(T+1) landed (counted, issued ~2 bodies ago -> free),
  //      frag reads(T) landed (covered by the MFMA cluster) ----
  if constexpr (T <= 5)      asm volatile("s_waitcnt vmcnt(6) lgkmcnt(0)" ::: "memory");
  else if constexpr (T == 6) asm volatile("s_waitcnt vmcnt(0) lgkmcnt(0)" ::: "memory");
  else                       asm volatile("s_waitcnt lgkmcnt(0)" ::: "memory");
  if constexpr (T < 7) __builtin_amdgcn_s_barrier();
  __builtin_amdgcn_sched_barrier(0);   // nothing crosses the body boundary
}

// ---------------- kernel 2: fused 128x256-tile GEMM + exp + row/col sums ----------------
__global__ __launch_bounds__(512, 2) void gemm_exp_kernel(
    const __bf16* __restrict__ Xn, const __bf16* __restrict__ Yn,
    float* __restrict__ rowsum, float* __restrict__ colsum,
    float* __restrict__ diag) {
  __shared__ __bf16 sm[73728];   // 144 KiB (3-buffer rotation)

  const int tid  = threadIdx.x;
  const int lane = tid & 63;
  const int w    = tid >> 6;
  const int wr   = w >> 2;            // 0..1  (64-row half)
  const int wc   = w & 3;             // 0..3  (64-col quarter)

  // XCD-aware swizzle (T1): 2048 blocks, 8 XCDs, bi-fast within an XCD chunk.
  const int id  = blockIdx.x;
  const int swz = (id & 7) * 256 + (id >> 3);
  const int bi  = swz & 63;           // 64 row tiles of 128
  const int bj  = swz >> 6;           // 32 col tiles of 256
  const int Ar = bi * 128;
  const int Br = bj * 256;

  const int l15 = lane & 15;
  const int g   = lane >> 4;          // 0..3
  const int sw  = g ^ (l15 & 7);      // swizzled chunk, ks=0

  // per-thread staging pointers (include source pre-swizzle)
  const int r0  = tid >> 3;
  const int sc0 = (tid & 7) ^ (r0 & 7);
  const __bf16* PA = Xn + (size_t)(Ar + r0) * DDIM + sc0 * 8;
  const __bf16* PB = Yn + (size_t)(Br + r0) * DDIM + sc0 * 8;

  // LDS read base regs (byte addrs), one pair per buffer; ks=1 -> ^64
  const uint32_t ldsb = (uint32_t)(uintptr_t)(lds_cbf16*)sm;
  uint32_t aB0r[3], aB1r[3], bB0r[3], bB1r[3];
  #pragma unroll
  for (int b = 0; b < 3; ++b) {
    aB0r[b] = ldsb + b*16384u + (uint32_t)((wr*64 + l15)*128 + sw*16);
    aB1r[b] = aB0r[b] ^ 64u;
    bB0r[b] = ldsb + 49152u + b*32768u + (uint32_t)((wc*64 + l15)*128 + sw*16);
    bB1r[b] = bB0r[b] ^ 64u;
  }

  bf16x8 aB[2][8], bB[2][8];
  f32x4 acc[4][4] = {};

  // ---- prologue: stage K-tiles 0 and 1; wait tile 0 only (counted) ----
  stage<0>(PA, PB, sm, tid);
  stage<1>(PA, PB, sm, tid);
  asm volatile("s_waitcnt vmcnt(6)" ::: "memory");
  __builtin_amdgcn_s_barrier();
  __builtin_amdgcn_sched_barrier(0);

  // ---- 8 K-tiles, MFMA trailing by one ----
  body<0>(PA, PB, sm, tid, aB0r, aB1r, bB0r, bB1r, aB, bB, acc);
  body<1>(PA, PB, sm, tid, aB0r, aB1r, bB0r, bB1r, aB, bB, acc);
  body<2>(PA, PB, sm, tid, aB0r, aB1r, bB0r, bB1r, aB, bB, acc);
  body<3>(PA, PB, sm, tid, aB0r, aB1r, bB0r, bB1r, aB, bB, acc);
  body<4>(PA, PB, sm, tid, aB0r, aB1r, bB0r, bB1r, aB, bB, acc);
  body<5>(PA, PB, sm, tid, aB0r, aB1r, bB0r, bB1r, aB, bB, acc);
  body<6>(PA, PB, sm, tid, aB0r, aB1r, bB0r, bB1r, aB, bB, acc);
  body<7>(PA, PB, sm, tid, aB0r, aB1r, bB0r, bB1r, aB, bB, acc);
  // tail: MFMA for K-tile 7 (bank 1)
  __builtin_amdgcn_s_setprio(1);
  #pragma unroll
  for (int mi = 0; mi < 4; ++mi)
    #pragma unroll
    for (int ni = 0; ni < 4; ++ni) {
      acc[mi][ni] = __builtin_amdgcn_mfma_f32_16x16x32_bf16(aB[1][mi*2+0], bB[1][ni*2+0], acc[mi][ni], 0,0,0);
      acc[mi][ni] = __builtin_amdgcn_mfma_f32_16x16x32_bf16(aB[1][mi*2+1], bB[1][ni*2+1], acc[mi][ni], 0,0,0);
    }
  __builtin_amdgcn_s_setprio(0);

  // ---------------- epilogue ----------------
  // C mapping (verified): row = RL[mi] + g*4 + r, col = CL[ni] + l15
  int RL[4], CL[4];
  #pragma unroll
  for (int m = 0; m < 4; ++m) RL[m] = wr*64 + m*16;
  #pragma unroll
  for (int n = 0; n < 4; ++n) CL[n] = wc*64 + n*16;

  // diag (pre-exp logits): tile contains diagonal iff bj == bi>>1
  if ((bi >> 1) == bj) {
    #pragma unroll
    for (int m = 0; m < 4; ++m)
      #pragma unroll
      for (int n = 0; n < 4; ++n)
        #pragma unroll
        for (int r = 0; r < 4; ++r) {
          const int grow = Ar + RL[m] + g*4 + r, gcol = Br + CL[n] + l15;
          if (grow == gcol) diag[grow] = TAU_INV * acc[m][n][r];
        }
  }

  // exp in place
  #pragma unroll
  for (int m = 0; m < 4; ++m)
    #pragma unroll
    for (int n = 0; n < 4; ++n)
      #pragma unroll
      for (int r = 0; r < 4; ++r)
        acc[m][n][r] = __expf(TAU_INV * acc[m][n][r]);

  // row sums: reduce over 4 n-frags + 16 cols (l15)
  #pragma unroll
  for (int m = 0; m < 4; ++m) {
    #pragma unroll
    for (int r = 0; r < 4; ++r) {
      float v = acc[m][0][r] + acc[m][1][r] + acc[m][2][r] + acc[m][3][r];
      v += __shfl_xor(v, 1); v += __shfl_xor(v, 2);
      v += __shfl_xor(v, 4); v += __shfl_xor(v, 8);
      if (l15 == 0) atomicAdd(&rowsum[Ar + RL[m] + g*4 + r], v);
    }
  }
  // col sums: reduce over 4 m-frags x 4 regs + 4 row-groups (g)
  #pragma unroll
  for (int n = 0; n < 4; ++n) {
    float v = 0.0f;
    #pragma unroll
    for (int m = 0; m < 4; ++m)
      #pragma unroll
      for (int r = 0; r < 4; ++r)
        v += acc[m][n][r];
    v += __shfl_xor(v, 16); v += __shfl_xor(v, 32);
    if (lane < 16) atomicAdd(&colsum[Br + CL[n] + l15], v);
  }
}

// ---------------- kernel 3: final scalar reduction (32 blocks, atomic) ----------------
__global__ __launch_bounds__(256) void finalize_kernel(
    const float* __restrict__ rowsum, const float* __restrict__ colsum,
    const float* __restrict__ diag, float* __restrict__ out) {
  const int i = blockIdx.x * 256 + (int)threadIdx.x;   // 32*256 == 8192 exactly
  float s = 0.5f * (logf(rowsum[i]) + logf(colsum[i])) - diag[i];
  #pragma unroll
  for (int off = 1; off < 64; off <<= 1) s += __shfl_xor(s, off);
  if ((threadIdx.x & 63) == 0) atomicAdd(out, s * (1.0f / NROWS));
}

extern "C" void kernel_launch(void* const* d_in, const int* in_sizes, int n_in,
                              void* d_out, int out_size, void* d_ws, size_t ws_size,
                              hipStream_t stream) {
  const float* x = (const float*)d_in[0];
  const float* y = (const float*)d_in[1];
  float* out = (float*)d_out;

  char* ws = (char*)d_ws;
  __bf16* Xn = (__bf16*)ws;                               // 8 MB
  __bf16* Yn = Xn + (size_t)NROWS * DDIM;                 // 8 MB
  float* rowsum = (float*)(ws + 2 * (size_t)NROWS * DDIM * sizeof(__bf16));
  float* colsum = rowsum + NROWS;
  float* diag   = colsum + NROWS;

  normalize_kernel<<<(2 * NROWS) / 4, 256, 0, stream>>>(x, y, Xn, Yn, rowsum, colsum, out);
  gemm_exp_kernel<<<2048, 512, 0, stream>>>(Xn, Yn, rowsum, colsum, diag);
  finalize_kernel<<<32, 256, 0, stream>>>(rowsum, colsum, diag, out);
}

// Round 8
// 170.844 us; speedup vs baseline: 1.1950x; 1.0453x over previous
//
#include <hip/hip_runtime.h>
#include <hip/hip_bf16.h>
#include <stdint.h>

// SymmetricLoss: symmetric InfoNCE over cosine logits.
// loss = mean_i[ 0.5*(log rowsum_i + log colsum_i) - S_ii ],
// S = Xn·Ynᵀ / tau.  |S|<=2 so exp needs no max subtraction.
//
// GEMM (R8 redesign around the LDS-bandwidth budget):
//  - mfma_f32_32x32x16_bf16, 64x128 per wave -> 384 B LDS-read per 16k FLOP
//    (vs 512 at 16x16), +20% FLOP/cyc.
//  - 128x256 block, 256 threads (4 waves 2x2), BK=32 double-buffered:
//    LDS = 48 KiB -> TWO blocks/CU. Cross-block TLP fills barrier-drain /
//    prologue / epilogue bubbles (m114 mechanism) that 1-block/CU rounds
//    R2-R7 all exposed.
//  - m97-style loop: stage(next) via global_load_lds, C++ LDS frag reads
//    (compiler emits fine-grained lgkmcnt), one __syncthreads per K-step.
//  - No swizzle: 32-row fragments on 64 B rows are naturally conflict-free.

#define NROWS 8192
#define DDIM  512
#define TAU_INV 2.0f

typedef __bf16 bf16x8 __attribute__((ext_vector_type(8)));
typedef __bf16 bf16x4 __attribute__((ext_vector_type(4)));
typedef float  f32x16 __attribute__((ext_vector_type(16)));

__device__ __forceinline__ void gload(const __bf16* src, __bf16* dst) {
  __builtin_amdgcn_global_load_lds((__attribute__((address_space(1))) void*)src,
      (__attribute__((address_space(3))) void*)dst, 16, 0, 0);
}

// ---------------- kernel 1: row-normalize x,y -> bf16 (+ zero accumulators) ----------------
__global__ __launch_bounds__(256) void normalize_kernel(
    const float* __restrict__ x, const float* __restrict__ y,
    __bf16* __restrict__ xn, __bf16* __restrict__ yn,
    float* __restrict__ rowsum, float* __restrict__ colsum,
    float* __restrict__ out) {
  const int idx = blockIdx.x * 256 + (int)threadIdx.x;
  if (idx < NROWS) { rowsum[idx] = 0.0f; colsum[idx] = 0.0f; }
  if (idx == 0) out[0] = 0.0f;

  const int wave = threadIdx.x >> 6;
  const int lane = threadIdx.x & 63;
  const int row  = blockIdx.x * 4 + wave;   // 0..16383: first 8192 = x, rest = y
  const float* src;
  __bf16* dst;
  if (row < NROWS) { src = x + (size_t)row * DDIM;           dst = xn + (size_t)row * DDIM; }
  else             { src = y + (size_t)(row - NROWS) * DDIM; dst = yn + (size_t)(row - NROWS) * DDIM; }

  const float4* s4 = (const float4*)src;
  float4 v0 = s4[lane];
  float4 v1 = s4[lane + 64];
  float ss = v0.x*v0.x + v0.y*v0.y + v0.z*v0.z + v0.w*v0.w
           + v1.x*v1.x + v1.y*v1.y + v1.z*v1.z + v1.w*v1.w;
  #pragma unroll
  for (int off = 1; off < 64; off <<= 1) ss += __shfl_xor(ss, off);
  const float rn = 1.0f / fmaxf(sqrtf(ss), 1e-8f);

  bf16x4 o0, o1;
  o0[0]=(__bf16)(v0.x*rn); o0[1]=(__bf16)(v0.y*rn); o0[2]=(__bf16)(v0.z*rn); o0[3]=(__bf16)(v0.w*rn);
  o1[0]=(__bf16)(v1.x*rn); o1[1]=(__bf16)(v1.y*rn); o1[2]=(__bf16)(v1.z*rn); o1[3]=(__bf16)(v1.w*rn);
  *(bf16x4*)(dst + 4*lane)       = o0;
  *(bf16x4*)(dst + 256 + 4*lane) = o1;
}

// ---------------- kernel 2: fused 128x256-tile GEMM + exp + row/col sums ----------------
// LDS elems: A bufs 2 x 4096 at [0,8192); B bufs 2 x 8192 at [8192,24576). 48 KiB.
__global__ __launch_bounds__(256, 2) void gemm_exp_kernel(
    const __bf16* __restrict__ Xn, const __bf16* __restrict__ Yn,
    float* __restrict__ rowsum, float* __restrict__ colsum,
    float* __restrict__ diag) {
  __shared__ __bf16 sm[24576];   // 48 KiB -> 2 blocks/CU

  const int tid  = threadIdx.x;
  const int lane = tid & 63;
  const int w    = tid >> 6;
  const int wr   = w >> 1;            // 0..1  (64-row half)
  const int wc   = w & 1;             // 0..1  (128-col half)

  // XCD-aware swizzle (T1): 2048 blocks, 8 XCDs, bi-fast within an XCD chunk.
  const int id  = blockIdx.x;
  const int swz = (id & 7) * 256 + (id >> 3);
  const int bi  = swz & 63;           // 64 row tiles of 128
  const int bj  = swz >> 6;           // 32 col tiles of 256
  const int Ar = bi * 128;
  const int Br = bj * 256;

  const int l31 = lane & 31;
  const int hi  = lane >> 5;          // 0..1

  // staging pointers: thread t covers row (t>>2), 16B chunk (t&3); rounds add 64 rows
  const int r0 = tid >> 2;
  const __bf16* PA = Xn + (size_t)(Ar + r0) * DDIM + (tid & 3) * 8;
  const __bf16* PB = Yn + (size_t)(Br + r0) * DDIM + (tid & 3) * 8;

  f32x16 acc[2][4] = {};

  // prologue: stage K-tile 0 into buf 0
  gload(PA,               sm + tid*8);
  gload(PA + 64*DDIM,     sm + 2048 + tid*8);
  gload(PB,               sm + 8192 + tid*8);
  gload(PB + 64*DDIM,     sm + 8192 + 2048 + tid*8);
  gload(PB + 128*DDIM,    sm + 8192 + 4096 + tid*8);
  gload(PB + 192*DDIM,    sm + 8192 + 6144 + tid*8);
  __syncthreads();

  #pragma unroll 1
  for (int kt = 0; kt < 16; ++kt) {
    const int buf = kt & 1;
    // stage K-tile kt+1 into the other buffer (issue early; lands by the barrier)
    if (kt < 15) {
      const __bf16* pa = PA + (kt + 1) * 32;
      const __bf16* pb = PB + (kt + 1) * 32;
      __bf16* da = sm + (buf ^ 1) * 4096;
      __bf16* db = sm + 8192 + (buf ^ 1) * 8192;
      gload(pa,            da + tid*8);
      gload(pa + 64*DDIM,  da + 2048 + tid*8);
      gload(pb,            db + tid*8);
      gload(pb + 64*DDIM,  db + 2048 + tid*8);
      gload(pb + 128*DDIM, db + 4096 + tid*8);
      gload(pb + 192*DDIM, db + 6144 + tid*8);
    }
    // fragments + MFMA (compiler schedules ds_reads with counted lgkm waits)
    const __bf16* As = sm + buf * 4096;
    const __bf16* Bs = sm + 8192 + buf * 8192;
    #pragma unroll
    for (int ks = 0; ks < 2; ++ks) {
      bf16x8 a[2], b[4];
      #pragma unroll
      for (int mi = 0; mi < 2; ++mi)
        a[mi] = *(const bf16x8*)(As + (wr*64 + mi*32 + l31)*32 + ks*16 + hi*8);
      #pragma unroll
      for (int ni = 0; ni < 4; ++ni)
        b[ni] = *(const bf16x8*)(Bs + (wc*128 + ni*32 + l31)*32 + ks*16 + hi*8);
      #pragma unroll
      for (int mi = 0; mi < 2; ++mi)
        #pragma unroll
        for (int ni = 0; ni < 4; ++ni)
          acc[mi][ni] = __builtin_amdgcn_mfma_f32_32x32x16_bf16(a[mi], b[ni], acc[mi][ni], 0, 0, 0);
    }
    __syncthreads();   // drains vmcnt (stage landed) + lgkm; protects both buffers
  }

  // ---------------- epilogue ----------------
  // 32x32 C/D mapping (verified m74/m101): col = l31, row = (reg&3) + 8*(reg>>2) + 4*hi
  // diag (pre-exp logits): tile contains diagonal iff bj == bi>>1
  if ((bi >> 1) == bj) {
    #pragma unroll
    for (int mi = 0; mi < 2; ++mi)
      #pragma unroll
      for (int ni = 0; ni < 4; ++ni)
        #pragma unroll
        for (int reg = 0; reg < 16; ++reg) {
          const int grow = Ar + wr*64 + mi*32 + (reg&3) + 8*(reg>>2) + 4*hi;
          const int gcol = Br + wc*128 + ni*32 + l31;
          if (grow == gcol) diag[grow] = TAU_INV * acc[mi][ni][reg];
        }
  }

  // exp in place
  #pragma unroll
  for (int mi = 0; mi < 2; ++mi)
    #pragma unroll
    for (int ni = 0; ni < 4; ++ni)
      #pragma unroll
      for (int reg = 0; reg < 16; ++reg)
        acc[mi][ni][reg] = __expf(TAU_INV * acc[mi][ni][reg]);

  // row sums: sum 4 ni + reduce over 32 cols (l31); one row per (mi,reg,hi)
  #pragma unroll
  for (int mi = 0; mi < 2; ++mi) {
    #pragma unroll
    for (int reg = 0; reg < 16; ++reg) {
      float v = acc[mi][0][reg] + acc[mi][1][reg] + acc[mi][2][reg] + acc[mi][3][reg];
      v += __shfl_xor(v, 1);  v += __shfl_xor(v, 2);
      v += __shfl_xor(v, 4);  v += __shfl_xor(v, 8); v += __shfl_xor(v, 16);
      if (l31 == 0) {
        const int grow = Ar + wr*64 + mi*32 + (reg&3) + 8*(reg>>2) + 4*hi;
        atomicAdd(&rowsum[grow], v);
      }
    }
  }
  // col sums: sum 2 mi x 16 regs per lane, fold the two hi-halves (same col)
  #pragma unroll
  for (int ni = 0; ni < 4; ++ni) {
    float v = 0.0f;
    #pragma unroll
    for (int mi = 0; mi < 2; ++mi)
      #pragma unroll
      for (int reg = 0; reg < 16; ++reg)
        v += acc[mi][ni][reg];
    v += __shfl_xor(v, 32);
    if (hi == 0) atomicAdd(&colsum[Br + wc*128 + ni*32 + l31], v);
  }
}

// ---------------- kernel 3: final scalar reduction (32 blocks, atomic) ----------------
__global__ __launch_bounds__(256) void finalize_kernel(
    const float* __restrict__ rowsum, const float* __restrict__ colsum,
    const float* __restrict__ diag, float* __restrict__ out) {
  const int i = blockIdx.x * 256 + (int)threadIdx.x;   // 32*256 == 8192 exactly
  float s = 0.5f * (logf(rowsum[i]) + logf(colsum[i])) - diag[i];
  #pragma unroll
  for (int off = 1; off < 64; off <<= 1) s += __shfl_xor(s, off);
  if ((threadIdx.x & 63) == 0) atomicAdd(out, s * (1.0f / NROWS));
}

extern "C" void kernel_launch(void* const* d_in, const int* in_sizes, int n_in,
                              void* d_out, int out_size, void* d_ws, size_t ws_size,
                              hipStream_t stream) {
  const float* x = (const float*)d_in[0];
  const float* y = (const float*)d_in[1];
  float* out = (float*)d_out;

  char* ws = (char*)d_ws;
  __bf16* Xn = (__bf16*)ws;                               // 8 MB
  __bf16* Yn = Xn + (size_t)NROWS * DDIM;                 // 8 MB
  float* rowsum = (float*)(ws + 2 * (size_t)NROWS * DDIM * sizeof(__bf16));
  float* colsum = rowsum + NROWS;
  float* diag   = colsum + NROWS;

  normalize_kernel<<<(2 * NROWS) / 4, 256, 0, stream>>>(x, y, Xn, Yn, rowsum, colsum, out);
  gemm_exp_kernel<<<2048, 256, 0, stream>>>(Xn, Yn, rowsum, colsum, diag);
  finalize_kernel<<<32, 256, 0, stream>>>(rowsum, colsum, diag, out);
}

// Round 9
// 168.927 us; speedup vs baseline: 1.2086x; 1.0114x over previous
//
#include <hip/hip_runtime.h>
#include <hip/hip_bf16.h>
#include <stdint.h>

// SymmetricLoss: symmetric InfoNCE over cosine logits.
// loss = mean_i[ 0.5*(log rowsum_i + log colsum_i) - S_ii ],
// S = Xn·Ynᵀ / tau.  |S|<=2 so exp needs no max subtraction.
//
// GEMM (R9 = R8 + pair-window XOR swizzle fixing 1.9e7 bank-conflict cycles):
//  - mfma_f32_32x32x16_bf16, 128x256 block, 256 threads (4 waves 2x2),
//    BK=32 double-buffered, 48 KiB LDS -> 2 blocks/CU (TLP fills bubbles).
//  - LDS layout: 128B windows (2 rows x 64B); 16B slot s = lc ^ ((r>>1)&7),
//    lc = (r&1)*4 + chunk. Staged linearly by global_load_lds with the
//    SOURCE pre-swizzled by the same involution (rule #21 both-sides);
//    fragment reads XOR the slot bits -> conflict-free b128 (8 lanes/quad
//    = the wave64 minimum).

#define NROWS 8192
#define DDIM  512
#define TAU_INV 2.0f

typedef __bf16 bf16x8 __attribute__((ext_vector_type(8)));
typedef __bf16 bf16x4 __attribute__((ext_vector_type(4)));
typedef float  f32x16 __attribute__((ext_vector_type(16)));

__device__ __forceinline__ void gload(const __bf16* src, __bf16* dst) {
  __builtin_amdgcn_global_load_lds((__attribute__((address_space(1))) void*)src,
      (__attribute__((address_space(3))) void*)dst, 16, 0, 0);
}

// ---------------- kernel 1: row-normalize x,y -> bf16 (+ zero accumulators) ----------------
__global__ __launch_bounds__(256) void normalize_kernel(
    const float* __restrict__ x, const float* __restrict__ y,
    __bf16* __restrict__ xn, __bf16* __restrict__ yn,
    float* __restrict__ rowsum, float* __restrict__ colsum,
    float* __restrict__ out) {
  const int idx = blockIdx.x * 256 + (int)threadIdx.x;
  if (idx < NROWS) { rowsum[idx] = 0.0f; colsum[idx] = 0.0f; }
  if (idx == 0) out[0] = 0.0f;

  const int wave = threadIdx.x >> 6;
  const int lane = threadIdx.x & 63;
  const int row  = blockIdx.x * 4 + wave;   // 0..16383: first 8192 = x, rest = y
  const float* src;
  __bf16* dst;
  if (row < NROWS) { src = x + (size_t)row * DDIM;           dst = xn + (size_t)row * DDIM; }
  else             { src = y + (size_t)(row - NROWS) * DDIM; dst = yn + (size_t)(row - NROWS) * DDIM; }

  const float4* s4 = (const float4*)src;
  float4 v0 = s4[lane];
  float4 v1 = s4[lane + 64];
  float ss = v0.x*v0.x + v0.y*v0.y + v0.z*v0.z + v0.w*v0.w
           + v1.x*v1.x + v1.y*v1.y + v1.z*v1.z + v1.w*v1.w;
  #pragma unroll
  for (int off = 1; off < 64; off <<= 1) ss += __shfl_xor(ss, off);
  const float rn = 1.0f / fmaxf(sqrtf(ss), 1e-8f);

  bf16x4 o0, o1;
  o0[0]=(__bf16)(v0.x*rn); o0[1]=(__bf16)(v0.y*rn); o0[2]=(__bf16)(v0.z*rn); o0[3]=(__bf16)(v0.w*rn);
  o1[0]=(__bf16)(v1.x*rn); o1[1]=(__bf16)(v1.y*rn); o1[2]=(__bf16)(v1.z*rn); o1[3]=(__bf16)(v1.w*rn);
  *(bf16x4*)(dst + 4*lane)       = o0;
  *(bf16x4*)(dst + 256 + 4*lane) = o1;
}

// ---------------- kernel 2: fused 128x256-tile GEMM + exp + row/col sums ----------------
// LDS bytes: A bufs 2 x 8192 at [0,16384); B bufs 2 x 16384 at [16384,49152). 48 KiB.
__global__ __launch_bounds__(256, 2) void gemm_exp_kernel(
    const __bf16* __restrict__ Xn, const __bf16* __restrict__ Yn,
    float* __restrict__ rowsum, float* __restrict__ colsum,
    float* __restrict__ diag) {
  __shared__ __bf16 sm[24576];   // 48 KiB -> 2 blocks/CU

  const int tid  = threadIdx.x;
  const int lane = tid & 63;
  const int w    = tid >> 6;
  const int wr   = w >> 1;            // 0..1  (64-row half)
  const int wc   = w & 1;             // 0..1  (128-col half)

  // XCD-aware swizzle (T1): 2048 blocks, 8 XCDs, bi-fast within an XCD chunk.
  const int id  = blockIdx.x;
  const int swz = (id & 7) * 256 + (id >> 3);
  const int bi  = swz & 63;           // 64 row tiles of 128
  const int bj  = swz >> 6;           // 32 col tiles of 256
  const int Ar = bi * 128;
  const int Br = bj * 256;

  const int l31 = lane & 31;
  const int hi  = lane >> 5;          // 0..1

  // ---- staging source pre-swizzle (involution): thread t -> (srow, sch) ----
  // lc = (t&7) ^ ((t>>3)&7); srow = 2*(t>>3) + lc>>2; sch = lc&3.
  // All gload segment offsets are multiples of 4096 B (32 windows, ≡0 mod 8).
  const int lc   = (tid & 7) ^ ((tid >> 3) & 7);
  const int srow = 2 * (tid >> 3) + (lc >> 2);
  const __bf16* PA = Xn + (size_t)(Ar + srow) * DDIM + (lc & 3) * 8;
  const __bf16* PB = Yn + (size_t)(Br + srow) * DDIM + (lc & 3) * 8;

  // ---- fragment read offsets (bf16 elements), ks=0; ks=1 XORs slot bit ----
  // elem = rowbase*32 + (l31>>1)*64 + slot*8, slot = ((l31&1)*4 + ks*2 + hi) ^ ((l31>>1)&7)
  const int swk   = (l31 >> 1) & 7;
  const int aoff0 = (l31 >> 1) * 64 + ((((l31 & 1) << 2) + hi) ^ swk) * 8 + wr * 2048;
  const int boff0 = (l31 >> 1) * 64 + ((((l31 & 1) << 2) + hi) ^ swk) * 8 + wc * 4096;

  f32x16 acc[2][4] = {};

  // prologue: stage K-tile 0 into buf 0 (LDS dest linear)
  gload(PA,               sm + tid*8);
  gload(PA + 64*DDIM,     sm + 2048 + tid*8);
  gload(PB,               sm + 8192 + tid*8);
  gload(PB + 64*DDIM,     sm + 8192 + 2048 + tid*8);
  gload(PB + 128*DDIM,    sm + 8192 + 4096 + tid*8);
  gload(PB + 192*DDIM,    sm + 8192 + 6144 + tid*8);
  __syncthreads();

  #pragma unroll 1
  for (int kt = 0; kt < 16; ++kt) {
    const int buf = kt & 1;
    // stage K-tile kt+1 into the other buffer (issue early; lands by the barrier)
    if (kt < 15) {
      const __bf16* pa = PA + (kt + 1) * 32;
      const __bf16* pb = PB + (kt + 1) * 32;
      __bf16* da = sm + (buf ^ 1) * 4096;
      __bf16* db = sm + 8192 + (buf ^ 1) * 8192;
      gload(pa,            da + tid*8);
      gload(pa + 64*DDIM,  da + 2048 + tid*8);
      gload(pb,            db + tid*8);
      gload(pb + 64*DDIM,  db + 2048 + tid*8);
      gload(pb + 128*DDIM, db + 4096 + tid*8);
      gload(pb + 192*DDIM, db + 6144 + tid*8);
    }
    // fragments + MFMA (compiler schedules ds_reads with counted lgkm waits)
    const __bf16* As = sm + buf * 4096;
    const __bf16* Bs = sm + 8192 + buf * 8192;
    #pragma unroll
    for (int ks = 0; ks < 2; ++ks) {
      bf16x8 a[2], b[4];
      #pragma unroll
      for (int mi = 0; mi < 2; ++mi)
        a[mi] = *(const bf16x8*)(As + ((aoff0 + mi*1024) ^ (ks*16)));
      #pragma unroll
      for (int ni = 0; ni < 4; ++ni)
        b[ni] = *(const bf16x8*)(Bs + ((boff0 + ni*1024) ^ (ks*16)));
      #pragma unroll
      for (int mi = 0; mi < 2; ++mi)
        #pragma unroll
        for (int ni = 0; ni < 4; ++ni)
          acc[mi][ni] = __builtin_amdgcn_mfma_f32_32x32x16_bf16(a[mi], b[ni], acc[mi][ni], 0, 0, 0);
    }
    __syncthreads();   // drains vmcnt (stage landed) + lgkm; protects both buffers
  }

  // ---------------- epilogue ----------------
  // 32x32 C/D mapping (verified m74/m101): col = l31, row = (reg&3) + 8*(reg>>2) + 4*hi
  // diag (pre-exp logits): tile contains diagonal iff bj == bi>>1
  if ((bi >> 1) == bj) {
    #pragma unroll
    for (int mi = 0; mi < 2; ++mi)
      #pragma unroll
      for (int ni = 0; ni < 4; ++ni)
        #pragma unroll
        for (int reg = 0; reg < 16; ++reg) {
          const int grow = Ar + wr*64 + mi*32 + (reg&3) + 8*(reg>>2) + 4*hi;
          const int gcol = Br + wc*128 + ni*32 + l31;
          if (grow == gcol) diag[grow] = TAU_INV * acc[mi][ni][reg];
        }
  }

  // exp in place
  #pragma unroll
  for (int mi = 0; mi < 2; ++mi)
    #pragma unroll
    for (int ni = 0; ni < 4; ++ni)
      #pragma unroll
      for (int reg = 0; reg < 16; ++reg)
        acc[mi][ni][reg] = __expf(TAU_INV * acc[mi][ni][reg]);

  // row sums: sum 4 ni + reduce over 32 cols (l31); one row per (mi,reg,hi)
  #pragma unroll
  for (int mi = 0; mi < 2; ++mi) {
    #pragma unroll
    for (int reg = 0; reg < 16; ++reg) {
      float v = acc[mi][0][reg] + acc[mi][1][reg] + acc[mi][2][reg] + acc[mi][3][reg];
      v += __shfl_xor(v, 1);  v += __shfl_xor(v, 2);
      v += __shfl_xor(v, 4);  v += __shfl_xor(v, 8); v += __shfl_xor(v, 16);
      if (l31 == 0) {
        const int grow = Ar + wr*64 + mi*32 + (reg&3) + 8*(reg>>2) + 4*hi;
        atomicAdd(&rowsum[grow], v);
      }
    }
  }
  // col sums: sum 2 mi x 16 regs per lane, fold the two hi-halves (same col)
  #pragma unroll
  for (int ni = 0; ni < 4; ++ni) {
    float v = 0.0f;
    #pragma unroll
    for (int mi = 0; mi < 2; ++mi)
      #pragma unroll
      for (int reg = 0; reg < 16; ++reg)
        v += acc[mi][ni][reg];
    v += __shfl_xor(v, 32);
    if (hi == 0) atomicAdd(&colsum[Br + wc*128 + ni*32 + l31], v);
  }
}

// ---------------- kernel 3: final scalar reduction (32 blocks, atomic) ----------------
__global__ __launch_bounds__(256) void finalize_kernel(
    const float* __restrict__ rowsum, const float* __restrict__ colsum,
    const float* __restrict__ diag, float* __restrict__ out) {
  const int i = blockIdx.x * 256 + (int)threadIdx.x;   // 32*256 == 8192 exactly
  float s = 0.5f * (logf(rowsum[i]) + logf(colsum[i])) - diag[i];
  #pragma unroll
  for (int off = 1; off < 64; off <<= 1) s += __shfl_xor(s, off);
  if ((threadIdx.x & 63) == 0) atomicAdd(out, s * (1.0f / NROWS));
}

extern "C" void kernel_launch(void* const* d_in, const int* in_sizes, int n_in,
                              void* d_out, int out_size, void* d_ws, size_t ws_size,
                              hipStream_t stream) {
  const float* x = (const float*)d_in[0];
  const float* y = (const float*)d_in[1];
  float* out = (float*)d_out;

  char* ws = (char*)d_ws;
  __bf16* Xn = (__bf16*)ws;                               // 8 MB
  __bf16* Yn = Xn + (size_t)NROWS * DDIM;                 // 8 MB
  float* rowsum = (float*)(ws + 2 * (size_t)NROWS * DDIM * sizeof(__bf16));
  float* colsum = rowsum + NROWS;
  float* diag   = colsum + NROWS;

  normalize_kernel<<<(2 * NROWS) / 4, 256, 0, stream>>>(x, y, Xn, Yn, rowsum, colsum, out);
  gemm_exp_kernel<<<2048, 256, 0, stream>>>(Xn, Yn, rowsum, colsum, diag);
  finalize_kernel<<<32, 256, 0, stream>>>(rowsum, colsum, diag, out);
}